// Round 8
// baseline (659.266 us; speedup 1.0000x reference)
//
#include <hip/hip_runtime.h>

#define DIMN 2048
#define NH 16
#define HDIM 128

typedef __attribute__((ext_vector_type(4))) float f32x4;
typedef __attribute__((ext_vector_type(8))) __bf16 bfx8;
typedef __attribute__((ext_vector_type(8))) unsigned short u16x8;
typedef __attribute__((ext_vector_type(2))) unsigned int u32x2;

__device__ __forceinline__ unsigned short f2bf(float f){
  unsigned u = __builtin_bit_cast(unsigned, f);
  u += 0x7fffu + ((u >> 16) & 1u);
  return (unsigned short)(u >> 16);
}
__device__ __forceinline__ float bf2f(unsigned short h){
  unsigned u = (unsigned)h << 16;
  return __builtin_bit_cast(float, u);
}
__device__ __forceinline__ unsigned cvt_pk_bf16(float lo, float hi){
  unsigned r;
  asm("v_cvt_pk_bf16_f32 %0, %1, %2" : "=v"(r) : "v"(lo), "v"(hi));
  return r;
}

__device__ __forceinline__ void gl_lds16(const void* g, void* l){
  __builtin_amdgcn_global_load_lds((const __attribute__((address_space(1))) void*)g,
                                   (__attribute__((address_space(3))) void*)l, 16, 0, 0);
}

#define MFMA16(a,b,c) __builtin_amdgcn_mfma_f32_16x16x32_bf16((a),(b),(c),0,0,0)

// ---------------- elementwise f32 -> bf16 cast ----------------
__global__ __launch_bounds__(256) void cast_bf16_kernel(const float* __restrict__ in,
                                                        unsigned short* __restrict__ out, int n8){
  int i = blockIdx.x*256 + threadIdx.x;
  if (i >= n8) return;
  const float4* p = (const float4*)(in + (size_t)i*8);
  float4 a = p[0], b = p[1];
  u16x8 o;
  o[0]=f2bf(a.x); o[1]=f2bf(a.y); o[2]=f2bf(a.z); o[3]=f2bf(a.w);
  o[4]=f2bf(b.x); o[5]=f2bf(b.y); o[6]=f2bf(b.z); o[7]=f2bf(b.w);
  *(u16x8*)(out + (size_t)i*8) = o;
}

// ---------------- k_cache (CACHE,H,HD) f32 -> kb[h][k][d] bf16 ----------------
__global__ __launch_bounds__(256) void kcache_kernel(const float* __restrict__ kc,
                                                     unsigned short* __restrict__ kb,
                                                     int R, int L_){
  const int gid = blockIdx.x*256 + threadIdx.x;
  if (gid >= R*256) return;
  const size_t idx = (size_t)gid * 8;
  const int k   = (int)(idx >> 11);
  const int rem = (int)(idx & 2047);
  const int hh  = rem >> 7, d = rem & 127;
  const float4* p = (const float4*)(kc + idx);
  float4 a = p[0], b = p[1];
  u16x8 o;
  o[0]=f2bf(a.x); o[1]=f2bf(a.y); o[2]=f2bf(a.z); o[3]=f2bf(a.w);
  o[4]=f2bf(b.x); o[5]=f2bf(b.y); o[6]=f2bf(b.z); o[7]=f2bf(b.w);
  *(u16x8*)(kb + (size_t)hh*L_*HDIM + (size_t)k*HDIM + d) = o;
}

// ---------------- (R,H,HD) f32 -> vt[h][d][koff+k] bf16 (transpose) ----------------
__global__ __launch_bounds__(256) void vtrans_kernel(const float* __restrict__ src,
                                                     unsigned short* __restrict__ vt,
                                                     int R, int koff, int L_){
  __shared__ __align__(16) unsigned short tile[32][72];
  const int kb0 = blockIdx.x * 64, db0 = blockIdx.y * 32, hh = blockIdx.z;
  const int t = threadIdx.x;
  const int kk = t >> 2, dd = (t & 3) * 8;
  const int k = kb0 + kk;
  if (k < R){
    const float* p = src + (size_t)k*DIMN + hh*HDIM + db0 + dd;
    float4 a = ((const float4*)p)[0], b = ((const float4*)p)[1];
    tile[dd+0][kk] = f2bf(a.x); tile[dd+1][kk] = f2bf(a.y);
    tile[dd+2][kk] = f2bf(a.z); tile[dd+3][kk] = f2bf(a.w);
    tile[dd+4][kk] = f2bf(b.x); tile[dd+5][kk] = f2bf(b.y);
    tile[dd+6][kk] = f2bf(b.z); tile[dd+7][kk] = f2bf(b.w);
  }
  __syncthreads();
  const int d = t >> 3, k0 = (t & 7) * 8;
  unsigned short* dst = vt + (size_t)hh*HDIM*L_ + (size_t)(db0+d)*L_ + koff + kb0 + k0;
  if (kb0 + k0 + 8 <= R){
    *(u16x8*)dst = *(const u16x8*)&tile[d][k0];
  } else {
    #pragma unroll
    for (int e=0;e<8;++e) if (kb0 + k0 + e < R) dst[e] = tile[d][k0+e];
  }
}

// ---------------- same but bf16 source (projected V) ----------------
__global__ __launch_bounds__(256) void vtrans_bf16_kernel(const unsigned short* __restrict__ src,
    unsigned short* __restrict__ vt, int R, int koff, int L_){
  __shared__ __align__(16) unsigned short tile[32][72];
  const int kb0 = blockIdx.x * 64, db0 = blockIdx.y * 32, hh = blockIdx.z;
  const int t = threadIdx.x;
  const int kk = t >> 2, dd = (t & 3) * 8;
  const int k = kb0 + kk;
  if (k < R){
    u16x8 a = *(const u16x8*)(src + (size_t)k*DIMN + hh*HDIM + db0 + dd);
    #pragma unroll
    for (int e=0;e<8;++e) tile[dd+e][kk] = a[e];
  }
  __syncthreads();
  const int d = t >> 3, k0 = (t & 7) * 8;
  unsigned short* dst = vt + (size_t)hh*HDIM*L_ + (size_t)(db0+d)*L_ + koff + kb0 + k0;
  if (kb0 + k0 + 8 <= R){
    *(u16x8*)dst = *(const u16x8*)&tile[d][k0];
  } else {
    #pragma unroll
    for (int e=0;e<8;++e) if (kb0 + k0 + e < R) dst[e] = tile[d][k0+e];
  }
}

// ---------------- fused rmsnorm + interleaved RoPE (bf16 in), bf16 head-major out ----
__global__ __launch_bounds__(256) void norm_rope_kernel(const unsigned short* __restrict__ lin,
    const float* __restrict__ g, const float* __restrict__ freqs, const int* __restrict__ cur,
    unsigned short* __restrict__ out, int S_, size_t head_stride, int row_off, float oscale){
  const int q = blockIdx.x, t = threadIdx.x;
  u16x8 v = *(const u16x8*)(lin + (size_t)q*DIMN + t*8);
  float x[8];
  #pragma unroll
  for (int e=0;e<8;++e) x[e] = bf2f(v[e]);
  float ss = 0.f;
  #pragma unroll
  for (int e=0;e<8;++e) ss += x[e]*x[e];
  for (int m=1;m<64;m<<=1) ss += __shfl_xor(ss, m);
  __shared__ float red[4];
  if ((t & 63) == 0) red[t>>6] = ss;
  __syncthreads();
  const float tot = red[0]+red[1]+red[2]+red[3];
  const float rstd = rsqrtf(tot * (1.0f/2048.0f) + 1e-6f);
  const int n0 = t*8;
  float xr[8];
  #pragma unroll
  for (int e=0;e<8;++e) xr[e] = x[e] * rstd * g[n0+e];
  const int pos = cur[0] + q;
  const int hh = n0 >> 7, d0 = n0 & 127;
  const float* fr = freqs + (size_t)pos * HDIM;
  float o[8];
  #pragma unroll
  for (int p=0;p<4;++p){
    const int j = (d0>>1) + p;
    const float c = fr[j], s = fr[64+j];
    o[2*p]   = xr[2*p]*c - xr[2*p+1]*s;
    o[2*p+1] = xr[2*p+1]*c + xr[2*p]*s;
  }
  u16x8 ov;
  #pragma unroll
  for (int e=0;e<8;++e) ov[e] = f2bf(o[e]*oscale);
  *(u16x8*)(out + (size_t)hh*head_stride + (size_t)(q+row_off)*HDIM + d0) = ov;
}

// ---------------- C[M,N] = A[M,K] * B[N,K]^T + bias, bf16 in fp32 out ----------------
__global__ __launch_bounds__(256,2) void gemm_bt(const unsigned short* __restrict__ A,
    const unsigned short* __restrict__ B, const float* __restrict__ bias,
    float* __restrict__ C, int M, int N, int K){
  __shared__ __align__(16) unsigned short As[128*64];
  __shared__ __align__(16) unsigned short Bs[128*64];
  const int t = threadIdx.x;
  const int w = t >> 6, lane = t & 63, lh = lane >> 4, ll = lane & 15;
  const int wr = w >> 1, wc = w & 1;
  const int m0 = blockIdx.y * 128, n0 = blockIdx.x * 128;
  const int srow = t >> 3;
  const int scb  = (t & 7) * 16;
  const int swc  = (scb ^ ((srow & 7) << 4)) >> 1;
  int arow[4]; size_t brow[4];
  #pragma unroll
  for (int c=0;c<4;++c){
    int r = m0 + c*32 + srow; if (r >= M) r = M-1;
    arow[c] = r;
    brow[c] = (size_t)(n0 + c*32 + srow);
  }
  const int xsw = (ll & 7) << 4;
  f32x4 acc[4][4] = {};
  const int nk = K >> 6;
  for (int kt = 0; kt < nk; ++kt){
    const int k0 = kt << 6;
    #pragma unroll
    for (int c=0;c<4;++c){
      gl_lds16(A + (size_t)arow[c]*K + k0 + swc, (char*)As + c*4096 + w*1024);
      gl_lds16(B + brow[c]*K       + k0 + swc, (char*)Bs + c*4096 + w*1024);
    }
    asm volatile("s_waitcnt vmcnt(0)" ::: "memory");
    __syncthreads();
    #pragma unroll
    for (int kk=0;kk<2;++kk){
      const int cb = kk*64 + lh*16;
      bfx8 a[4], b[4];
      #pragma unroll
      for (int i=0;i<4;++i)
        a[i] = *(const bfx8*)((const char*)As + (wr*64 + i*16 + ll)*128 + (cb ^ xsw));
      #pragma unroll
      for (int j=0;j<4;++j)
        b[j] = *(const bfx8*)((const char*)Bs + (wc*64 + j*16 + ll)*128 + (cb ^ xsw));
      #pragma unroll
      for (int i=0;i<4;++i)
        #pragma unroll
        for (int j=0;j<4;++j)
          acc[i][j] = MFMA16(a[i], b[j], acc[i][j]);
    }
    __syncthreads();
  }
  #pragma unroll
  for (int i=0;i<4;++i){
    #pragma unroll
    for (int j=0;j<4;++j){
      const int col = n0 + wc*64 + j*16 + ll;
      const float bb = bias[col];
      #pragma unroll
      for (int r=0;r<4;++r){
        const int row = m0 + wr*64 + i*16 + lh*4 + r;
        if (row < M) C[(size_t)row*N + col] = acc[i][j][r] + bb;
      }
    }
  }
}

// ---------------- fused QKV gemm: z selects weight/bias/output; bf16 out ----------------
__global__ __launch_bounds__(256,2) void gemm_qkv(const unsigned short* __restrict__ A,
    const unsigned short* __restrict__ B0, const unsigned short* __restrict__ B1,
    const unsigned short* __restrict__ B2, const float* __restrict__ g0,
    const float* __restrict__ g1, const float* __restrict__ g2,
    unsigned short* __restrict__ C0, unsigned short* __restrict__ C1,
    unsigned short* __restrict__ C2, int M, int N, int K){
  const int zz = blockIdx.z;
  const unsigned short* B = (zz==0) ? B0 : (zz==1) ? B1 : B2;
  const float* bias       = (zz==0) ? g0 : (zz==1) ? g1 : g2;
  unsigned short* C       = (zz==0) ? C0 : (zz==1) ? C1 : C2;
  __shared__ __align__(16) unsigned short As[128*64];
  __shared__ __align__(16) unsigned short Bs[128*64];
  const int t = threadIdx.x;
  const int w = t >> 6, lane = t & 63, lh = lane >> 4, ll = lane & 15;
  const int wr = w >> 1, wc = w & 1;
  const int m0 = blockIdx.y * 128, n0 = blockIdx.x * 128;
  const int srow = t >> 3;
  const int scb  = (t & 7) * 16;
  const int swc  = (scb ^ ((srow & 7) << 4)) >> 1;
  int arow[4]; size_t brow[4];
  #pragma unroll
  for (int c=0;c<4;++c){
    int r = m0 + c*32 + srow; if (r >= M) r = M-1;
    arow[c] = r;
    brow[c] = (size_t)(n0 + c*32 + srow);
  }
  const int xsw = (ll & 7) << 4;
  f32x4 acc[4][4] = {};
  const int nk = K >> 6;
  for (int kt = 0; kt < nk; ++kt){
    const int k0 = kt << 6;
    #pragma unroll
    for (int c=0;c<4;++c){
      gl_lds16(A + (size_t)arow[c]*K + k0 + swc, (char*)As + c*4096 + w*1024);
      gl_lds16(B + brow[c]*K       + k0 + swc, (char*)Bs + c*4096 + w*1024);
    }
    asm volatile("s_waitcnt vmcnt(0)" ::: "memory");
    __syncthreads();
    #pragma unroll
    for (int kk=0;kk<2;++kk){
      const int cb = kk*64 + lh*16;
      bfx8 a[4], b[4];
      #pragma unroll
      for (int i=0;i<4;++i)
        a[i] = *(const bfx8*)((const char*)As + (wr*64 + i*16 + ll)*128 + (cb ^ xsw));
      #pragma unroll
      for (int j=0;j<4;++j)
        b[j] = *(const bfx8*)((const char*)Bs + (wc*64 + j*16 + ll)*128 + (cb ^ xsw));
      #pragma unroll
      for (int i=0;i<4;++i)
        #pragma unroll
        for (int j=0;j<4;++j)
          acc[i][j] = MFMA16(a[i], b[j], acc[i][j]);
    }
    __syncthreads();
  }
  #pragma unroll
  for (int i=0;i<4;++i){
    #pragma unroll
    for (int j=0;j<4;++j){
      const int col = n0 + wc*64 + j*16 + ll;
      const float bb = bias[col];
      #pragma unroll
      for (int r=0;r<4;++r){
        const int row = m0 + wr*64 + i*16 + lh*4 + r;
        if (row < M) C[(size_t)row*N + col] = f2bf(acc[i][j][r] + bb);
      }
    }
  }
}

// ---------------- flash attention, 48KB LDS, reg-diet time-shared staging ----------------
// 4 waves, 128 q-rows/block, 64-key tiles, KV-split via z. XCD-chunked swizzle (T1).
// Single K buf + single V buf, staggered writes at the two barriers:
//   bar1 -> QK^T(Ks) -> Vs<-sreg(V[kt]) -> sreg<-K[kt+1] -> softmax
//   bar2 -> P,PV(Vs) -> Ks<-sreg(K[kt+1]) -> sreg<-V[kt+1]
// ONE sreg[4] block time-shared between K and V (halves staging VGPRs).
// launch_bounds(256,3): target 3 waves/SIMD (total regs <= 170 incl 64 acc).
__global__ __launch_bounds__(256,3) void attn_kernel(const unsigned short* __restrict__ Q,
    const unsigned short* __restrict__ K, const unsigned short* __restrict__ VT,
    unsigned short* __restrict__ O, float* __restrict__ pacc, float* __restrict__ pml,
    int S_, int L_, int CLn, int nx, int nsplit){
  __shared__ __align__(16) unsigned short Ks[64*128];
  __shared__ __align__(16) unsigned short Vs[128*64];
  __shared__ __align__(16) unsigned short Ps[4][32*64];
  const int nwg = gridDim.x;
  const int swzid = (blockIdx.x & 7)*(nwg >> 3) + (blockIdx.x >> 3);
  const int xq = swzid % nx;
  const int rest = swzid / nx;
  const int hh = rest % NH;
  const int z  = rest / NH;
  const int q0 = xq * 128;
  const int t = threadIdx.x, w = t >> 6, lane = t & 63, lh = lane >> 4, ll = lane & 15;
  const int xsw = (ll & 7) << 4;
  char* Pw = (char*)Ps[w];
  const unsigned short* Qh = Q  + (size_t)hh*S_*HDIM;
  const unsigned short* Kh = K  + (size_t)hh*L_*HDIM;
  const unsigned short* Vh = VT + (size_t)hh*HDIM*L_;
  bfx8 qf[2][4];
  #pragma unroll
  for (int i=0;i<2;++i){
    int qr = q0 + w*32 + i*16 + ll; if (qr >= S_) qr = S_ - 1;
    #pragma unroll
    for (int kk=0;kk<4;++kk)
      qf[i][kk] = *(const bfx8*)(Qh + (size_t)qr*HDIM + kk*32 + lh*8);
  }
  f32x4 acc[2][8] = {};
  float m_st[2], l_st[2];
  m_st[0] = m_st[1] = -1e20f;
  l_st[0] = l_st[1] = 0.f;
  const int wrow0 = q0 + w*32;
  int qlast = q0 + 127; if (qlast >= S_) qlast = S_ - 1;
  const int kend = CLn + qlast + 1;
  const int nt = (kend + 63) >> 6;
  const int tps = (nt + nsplit - 1) / nsplit;
  const int t0 = z * tps;
  int t1 = t0 + tps; if (t1 > nt) t1 = nt;
  const int ksrow = t >> 4, kchunk = t & 15;
  const int vsrow = t >> 3, vchunk = t & 7;
  const int myq[2] = { wrow0 + ll, wrow0 + 16 + ll };
  const int last = nt - 1;   // only globally-last tile needs clamped loads (L%8==0)

  u16x8 sreg[4];   // time-shared K/V staging block
  auto load_K = [&](int ktile){
    const int kv0 = ktile << 6;
    if (ktile == last){
      #pragma unroll
      for (int c=0;c<4;++c){
        int krow = kv0 + c*16 + ksrow; if (krow >= L_) krow = L_ - 1;
        sreg[c] = *(const u16x8*)(Kh + (size_t)krow*HDIM + kchunk*8);
      }
    } else {
      #pragma unroll
      for (int c=0;c<4;++c)
        sreg[c] = *(const u16x8*)(Kh + (size_t)(kv0 + c*16 + ksrow)*HDIM + kchunk*8);
    }
  };
  auto load_V = [&](int ktile){
    const int kv0 = ktile << 6;
    int vcol = kv0 + vchunk*8;
    if (ktile == last && vcol > L_ - 8) vcol = L_ - 8;
    #pragma unroll
    for (int c=0;c<4;++c)
      sreg[c] = *(const u16x8*)(Vh + (size_t)(c*32 + vsrow)*L_ + vcol);
  };
  auto write_K = [&](){
    #pragma unroll
    for (int c=0;c<4;++c)
      *(u16x8*)((char*)Ks + (c*16 + ksrow)*256 + ((kchunk*16) ^ ((ksrow & 7) << 4))) = sreg[c];
  };
  auto write_V = [&](){
    #pragma unroll
    for (int c=0;c<4;++c)
      *(u16x8*)((char*)Vs + (c*32 + vsrow)*128 + ((vchunk*16) ^ ((vsrow & 7) << 4))) = sreg[c];
  };

  if (t0 < t1){
    load_K(t0); write_K();   // Ks <- K[t0]
    load_V(t0);              // sreg <- V[t0]
  }
  for (int kt = t0; kt < t1; ++kt){
    const int kv0 = kt << 6;
    __syncthreads();   // bar1: Ks[kt] visible; prev tile's PV done reading Vs
    // QK^T (swapped): C[row=k][col=q=ll], scores pre-scaled to exp2 domain
    f32x4 sc[2][4] = {};
    #pragma unroll
    for (int kk=0;kk<4;++kk){
      const int cb = kk*64 + lh*16;
      #pragma unroll
      for (int j=0;j<4;++j){
        bfx8 kf = *(const bfx8*)((const char*)Ks + (j*16 + ll)*256 + (cb ^ xsw));
        sc[0][j] = MFMA16(kf, qf[0][kk], sc[0][j]);
        sc[1][j] = MFMA16(kf, qf[1][kk], sc[1][j]);
      }
    }
    write_V();                       // Vs <- V[kt] (sreg dies)
    if (kt + 1 < t1) load_K(kt + 1); // sreg <- K[kt+1], lands under softmax+bar2+PV
    // causal mask (scale folded into Q)
    const bool needmask = (kv0 + 63 > CLn + wrow0);
    if (needmask){
      #pragma unroll
      for (int i=0;i<2;++i){
        const int lim = CLn + myq[i];
        #pragma unroll
        for (int j=0;j<4;++j)
          #pragma unroll
          for (int r=0;r<4;++r){
            const int key = kv0 + j*16 + lh*4 + r;
            if (key > lim) sc[i][j][r] = -1e30f;
          }
      }
    }
    // row max
    float m_t[2];
    #pragma unroll
    for (int i=0;i<2;++i){
      float mt = sc[i][0][0];
      #pragma unroll
      for (int j=0;j<4;++j)
        #pragma unroll
        for (int r=0;r<4;++r) mt = fmaxf(mt, sc[i][j][r]);
      mt = fmaxf(mt, __shfl_xor(mt, 16));
      mt = fmaxf(mt, __shfl_xor(mt, 32));
      m_t[i] = fmaxf(mt, -1e20f);
    }
    const float mdiff = fmaxf(m_t[0] - m_st[0], m_t[1] - m_st[1]);
    if (!__all(mdiff <= 11.54f)){   // defer-max (8 nats in log2 domain)
      float corr[2];
      #pragma unroll
      for (int i=0;i<2;++i){
        const float mn = fmaxf(m_st[i], m_t[i]);
        corr[i] = exp2f(m_st[i] - mn);
        m_st[i] = mn;
        l_st[i] *= corr[i];
      }
      #pragma unroll
      for (int i=0;i<2;++i)
        #pragma unroll
        for (int r=0;r<4;++r){
          const float ca = __shfl(corr[i], lh*4 + r);
          #pragma unroll
          for (int jn=0;jn<8;++jn) acc[i][jn][r] *= ca;
        }
    }
    // P = exp2(sc - m), row sums
    #pragma unroll
    for (int i=0;i<2;++i){
      float rs = 0.f;
      #pragma unroll
      for (int j=0;j<4;++j)
        #pragma unroll
        for (int r=0;r<4;++r){
          const float pv = exp2f(sc[i][j][r] - m_st[i]);
          sc[i][j][r] = pv;
          rs += pv;
        }
      rs += __shfl_xor(rs, 16);
      rs += __shfl_xor(rs, 32);
      l_st[i] += rs;
    }
    __syncthreads();   // bar2: Vs[kt] visible; all waves done QK^T reads of Ks
    // P-store via cvt_pk (wave-private buffer)
    #pragma unroll
    for (int i=0;i<2;++i)
      #pragma unroll
      for (int j=0;j<4;++j){
        u32x2 pk;
        pk[0] = cvt_pk_bf16(sc[i][j][0], sc[i][j][1]);
        pk[1] = cvt_pk_bf16(sc[i][j][2], sc[i][j][3]);
        *(u32x2*)(Pw + (i*16 + ll)*128 + ((j*32 + lh*8) ^ xsw)) = pk;
      }
    // PV
    #pragma unroll
    for (int kk=0;kk<2;++kk){
      const int cb = kk*64 + lh*16;
      bfx8 af0 = *(const bfx8*)(Pw + (ll)*128      + (cb ^ xsw));
      bfx8 af1 = *(const bfx8*)(Pw + (16 + ll)*128 + (cb ^ xsw));
      #pragma unroll
      for (int jn=0;jn<8;++jn){
        bfx8 vf = *(const bfx8*)((const char*)Vs + (jn*16 + ll)*128 + (cb ^ xsw));
        acc[0][jn] = MFMA16(af0, vf, acc[0][jn]);
        acc[1][jn] = MFMA16(af1, vf, acc[1][jn]);
      }
    }
    if (kt + 1 < t1){
      write_K();        // Ks <- K[kt+1] (safe: all waves passed bar2 = done with Ks)
      load_V(kt + 1);   // sreg <- V[kt+1], lands under bar1+QK^T of next iter
    }
  }
  // epilogue
  if (nsplit == 1){
    #pragma unroll
    for (int i=0;i<2;++i){
      const float linv = 1.0f / l_st[i];
      #pragma unroll
      for (int r=0;r<4;++r){
        const float inv = __shfl(linv, lh*4 + r);
        const int qr = wrow0 + i*16 + lh*4 + r;
        if (qr < S_){
          #pragma unroll
          for (int jn=0;jn<8;++jn)
            O[(size_t)qr*DIMN + hh*HDIM + jn*16 + ll] = f2bf(acc[i][jn][r]*inv);
        }
      }
    }
  } else {
    #pragma unroll
    for (int i=0;i<2;++i){
      #pragma unroll
      for (int r=0;r<4;++r){
        const int qr = wrow0 + i*16 + lh*4 + r;
        if (qr < S_){
          const size_t rid = ((size_t)z*NH + hh)*S_ + qr;
          float* dst = pacc + rid*128;
          #pragma unroll
          for (int jn=0;jn<8;++jn) dst[jn*16 + ll] = acc[i][jn][r];
        }
      }
      if (lane < 16){
        const int qr2 = myq[i];
        if (qr2 < S_){
          const size_t rid2 = ((size_t)z*NH + hh)*S_ + qr2;
          pml[rid2*2]   = m_st[i];
          pml[rid2*2+1] = l_st[i];
        }
      }
    }
  }
}

// ---------------- combine partials -> ob bf16 (exp2 domain m) ----------------
__global__ __launch_bounds__(256) void combine_kernel(const float* __restrict__ pacc,
    const float* __restrict__ pml, unsigned short* __restrict__ ob, int S_, int nsplit){
  const int t = threadIdx.x;
  const int rid = blockIdx.x*2 + (t >> 7);   // hh*S_+q
  if (rid >= S_*NH) return;
  const int d = t & 127;
  const int hh = rid / S_;
  const int q  = rid - hh*S_;
  float M = -1e20f;
  for (int s=0; s<nsplit; ++s)
    M = fmaxf(M, pml[((size_t)s*NH*S_ + rid)*2]);
  float lt = 0.f, o = 0.f;
  for (int s=0; s<nsplit; ++s){
    const float m = pml[((size_t)s*NH*S_ + rid)*2];
    const float l = pml[((size_t)s*NH*S_ + rid)*2 + 1];
    const float wgt = exp2f(m - M);
    lt += l * wgt;
    o  += pacc[((size_t)s*NH*S_ + rid)*128 + d] * wgt;
  }
  if (lt == 0.f) lt = 1.f;
  ob[(size_t)q*DIMN + hh*HDIM + d] = f2bf(o / lt);
}

extern "C" void kernel_launch(void* const* d_in, const int* in_sizes, int n_in,
                              void* d_out, int out_size, void* d_ws, size_t ws_size,
                              hipStream_t stream){
  const float* x       = (const float*)d_in[0];
  const float* freqs   = (const float*)d_in[1];
  const float* k_cache = (const float*)d_in[2];
  const float* v_cache = (const float*)d_in[3];
  const float* Wq = (const float*)d_in[4];
  const float* bq = (const float*)d_in[5];
  const float* Wk = (const float*)d_in[6];
  const float* bk = (const float*)d_in[7];
  const float* Wv = (const float*)d_in[8];
  const float* bv = (const float*)d_in[9];
  const float* Wo = (const float*)d_in[10];
  const float* bo = (const float*)d_in[11];
  const float* gq = (const float*)d_in[12];
  const float* gk = (const float*)d_in[13];
  const int*   cur = (const int*)d_in[14];

  const int S = in_sizes[0] / DIMN;
  const int CACHE_ = in_sizes[2] / DIMN;
  const int L = CACHE_ + S;
  const int CLn = L - S;

  auto al = [](size_t n){ return (n + 255) & ~(size_t)255; };
  char* base = (char*)d_ws;
  size_t off = 0;
  auto take = [&](size_t n){ char* r = base + off; off += al(n); return r; };
  // persistent:
  unsigned short* xb  = (unsigned short*)take((size_t)S*DIMN*2);
  unsigned short* Wob = (unsigned short*)take((size_t)DIMN*DIMN*2);
  unsigned short* qb  = (unsigned short*)take((size_t)NH*S*HDIM*2);
  unsigned short* kb  = (unsigned short*)take((size_t)NH*L*HDIM*2);
  unsigned short* vtb = (unsigned short*)take((size_t)NH*HDIM*L*2);
  unsigned short* ob  = (unsigned short*)take((size_t)S*DIMN*2);
  const size_t ubase = off;
  // union pool A: transients (dead before attn): lin0/1/2 (bf16) + Wq/Wk/Wv (bf16)
  const size_t l_sz = al((size_t)S*DIMN*2);
  const size_t w_sz = al((size_t)DIMN*DIMN*2);
  unsigned short* lin0 = (unsigned short*)(base + ubase);
  unsigned short* lin1 = (unsigned short*)(base + ubase + l_sz);
  unsigned short* lin2 = (unsigned short*)(base + ubase + 2*l_sz);
  unsigned short* Wqb  = (unsigned short*)(base + ubase + 3*l_sz);
  unsigned short* Wkb  = (unsigned short*)(base + ubase + 3*l_sz + w_sz);
  unsigned short* Wvb  = (unsigned short*)(base + ubase + 3*l_sz + 2*w_sz);
  const size_t trans_sz = 3*l_sz + 3*w_sz;
  // union pool B: attention partials
  auto pool_sz = [&](int ns){
    return al((size_t)ns*NH*S*HDIM*4) + al((size_t)ns*NH*S*2*4);
  };
  int nsplit = 1;
  if (ubase + (trans_sz > pool_sz(4) ? trans_sz : pool_sz(4)) <= ws_size) nsplit = 4;
  else if (ubase + (trans_sz > pool_sz(2) ? trans_sz : pool_sz(2)) <= ws_size) nsplit = 2;
  if (ubase + trans_sz > ws_size) return;
  float* pacc = (float*)(base + ubase);
  float* pml  = (float*)(base + ubase + al((size_t)nsplit*NH*S*HDIM*4));

  const int wn8 = DIMN*DIMN/8;
  cast_bf16_kernel<<<(S*DIMN/8+255)/256, 256, 0, stream>>>(x,  xb,  S*DIMN/8);
  cast_bf16_kernel<<<(wn8+255)/256, 256, 0, stream>>>(Wq, Wqb, wn8);
  cast_bf16_kernel<<<(wn8+255)/256, 256, 0, stream>>>(Wk, Wkb, wn8);
  cast_bf16_kernel<<<(wn8+255)/256, 256, 0, stream>>>(Wv, Wvb, wn8);
  cast_bf16_kernel<<<(wn8+255)/256, 256, 0, stream>>>(Wo, Wob, wn8);
  kcache_kernel<<<CACHE_, 256, 0, stream>>>(k_cache, kb, CACHE_, L);
  vtrans_kernel<<<dim3((CACHE_+63)/64, 4, NH), 256, 0, stream>>>(v_cache, vtb, CACHE_, 0, L);

  const int mb = (S+127)/128;
  gemm_qkv<<<dim3(DIMN/128, mb, 3), 256, 0, stream>>>(xb, Wqb, Wkb, Wvb, bq, bk, bv,
                                                      lin0, lin1, lin2, S, DIMN, DIMN);
  const float qsc = 0.08838834764831845f * 1.4426950408889634f;
  norm_rope_kernel<<<S, 256, 0, stream>>>(lin0, gq, freqs, cur, qb, S, (size_t)S*HDIM, 0, qsc);
  norm_rope_kernel<<<S, 256, 0, stream>>>(lin1, gk, freqs, cur, kb, S, (size_t)L*HDIM, CACHE_, 1.0f);
  vtrans_bf16_kernel<<<dim3((S+63)/64, 4, NH), 256, 0, stream>>>(lin2, vtb, S, CACHE_, L);

  const int nx = (S+127)/128;
  attn_kernel<<<nx*NH*nsplit, 256, 0, stream>>>(qb, kb, vtb, ob,
                                                pacc, pml, S, L, CLn, nx, nsplit);
  if (nsplit > 1)
    combine_kernel<<<(S*NH+1)/2, 256, 0, stream>>>(pacc, pml, ob, S, nsplit);
  gemm_bt<<<dim3(DIMN/128, mb), 256, 0, stream>>>(ob, Wob, bo, (float*)d_out, S, DIMN, DIMN);
}

// Round 9
// 523.961 us; speedup vs baseline: 1.2582x; 1.2582x over previous
//
#include <hip/hip_runtime.h>

#define DIMN 2048
#define NH 16
#define HDIM 128

typedef __attribute__((ext_vector_type(4))) float f32x4;
typedef __attribute__((ext_vector_type(8))) __bf16 bfx8;
typedef __attribute__((ext_vector_type(4))) __bf16 bf16x4;
typedef __attribute__((ext_vector_type(8))) unsigned short u16x8;

__device__ __forceinline__ unsigned short f2bf(float f){
  unsigned u = __builtin_bit_cast(unsigned, f);
  u += 0x7fffu + ((u >> 16) & 1u);
  return (unsigned short)(u >> 16);
}
__device__ __forceinline__ float bf2f(unsigned short h){
  unsigned u = (unsigned)h << 16;
  return __builtin_bit_cast(float, u);
}

__device__ __forceinline__ void gl_lds16(const void* g, void* l){
  __builtin_amdgcn_global_load_lds((const __attribute__((address_space(1))) void*)g,
                                   (__attribute__((address_space(3))) void*)l, 16, 0, 0);
}

#define MFMA16(a,b,c) __builtin_amdgcn_mfma_f32_16x16x32_bf16((a),(b),(c),0,0,0)

// ---------------- elementwise f32 -> bf16 cast ----------------
__global__ __launch_bounds__(256) void cast_bf16_kernel(const float* __restrict__ in,
                                                        unsigned short* __restrict__ out, int n8){
  int i = blockIdx.x*256 + threadIdx.x;
  if (i >= n8) return;
  const float4* p = (const float4*)(in + (size_t)i*8);
  float4 a = p[0], b = p[1];
  u16x8 o;
  o[0]=f2bf(a.x); o[1]=f2bf(a.y); o[2]=f2bf(a.z); o[3]=f2bf(a.w);
  o[4]=f2bf(b.x); o[5]=f2bf(b.y); o[6]=f2bf(b.z); o[7]=f2bf(b.w);
  *(u16x8*)(out + (size_t)i*8) = o;
}

// ---------------- k_cache (CACHE,H,HD) f32 -> kb[h][k][d] bf16 ----------------
__global__ __launch_bounds__(256) void kcache_kernel(const float* __restrict__ kc,
                                                     unsigned short* __restrict__ kb,
                                                     int R, int L_){
  const int gid = blockIdx.x*256 + threadIdx.x;
  if (gid >= R*256) return;
  const size_t idx = (size_t)gid * 8;
  const int k   = (int)(idx >> 11);
  const int rem = (int)(idx & 2047);
  const int hh  = rem >> 7, d = rem & 127;
  const float4* p = (const float4*)(kc + idx);
  float4 a = p[0], b = p[1];
  u16x8 o;
  o[0]=f2bf(a.x); o[1]=f2bf(a.y); o[2]=f2bf(a.z); o[3]=f2bf(a.w);
  o[4]=f2bf(b.x); o[5]=f2bf(b.y); o[6]=f2bf(b.z); o[7]=f2bf(b.w);
  *(u16x8*)(kb + (size_t)hh*L_*HDIM + (size_t)k*HDIM + d) = o;
}

// ---------------- (R,H,HD) f32 -> vt[h][d][koff+k] bf16 (transpose) ----------------
__global__ __launch_bounds__(256) void vtrans_kernel(const float* __restrict__ src,
                                                     unsigned short* __restrict__ vt,
                                                     int R, int koff, int L_){
  __shared__ __align__(16) unsigned short tile[32][72];
  const int kb0 = blockIdx.x * 64, db0 = blockIdx.y * 32, hh = blockIdx.z;
  const int t = threadIdx.x;
  const int kk = t >> 2, dd = (t & 3) * 8;
  const int k = kb0 + kk;
  if (k < R){
    const float* p = src + (size_t)k*DIMN + hh*HDIM + db0 + dd;
    float4 a = ((const float4*)p)[0], b = ((const float4*)p)[1];
    tile[dd+0][kk] = f2bf(a.x); tile[dd+1][kk] = f2bf(a.y);
    tile[dd+2][kk] = f2bf(a.z); tile[dd+3][kk] = f2bf(a.w);
    tile[dd+4][kk] = f2bf(b.x); tile[dd+5][kk] = f2bf(b.y);
    tile[dd+6][kk] = f2bf(b.z); tile[dd+7][kk] = f2bf(b.w);
  }
  __syncthreads();
  const int d = t >> 3, k0 = (t & 7) * 8;
  unsigned short* dst = vt + (size_t)hh*HDIM*L_ + (size_t)(db0+d)*L_ + koff + kb0 + k0;
  if (kb0 + k0 + 8 <= R){
    *(u16x8*)dst = *(const u16x8*)&tile[d][k0];
  } else {
    #pragma unroll
    for (int e=0;e<8;++e) if (kb0 + k0 + e < R) dst[e] = tile[d][k0+e];
  }
}

// ---------------- same but bf16 source (projected V) ----------------
__global__ __launch_bounds__(256) void vtrans_bf16_kernel(const unsigned short* __restrict__ src,
    unsigned short* __restrict__ vt, int R, int koff, int L_){
  __shared__ __align__(16) unsigned short tile[32][72];
  const int kb0 = blockIdx.x * 64, db0 = blockIdx.y * 32, hh = blockIdx.z;
  const int t = threadIdx.x;
  const int kk = t >> 2, dd = (t & 3) * 8;
  const int k = kb0 + kk;
  if (k < R){
    u16x8 a = *(const u16x8*)(src + (size_t)k*DIMN + hh*HDIM + db0 + dd);
    #pragma unroll
    for (int e=0;e<8;++e) tile[dd+e][kk] = a[e];
  }
  __syncthreads();
  const int d = t >> 3, k0 = (t & 7) * 8;
  unsigned short* dst = vt + (size_t)hh*HDIM*L_ + (size_t)(db0+d)*L_ + koff + kb0 + k0;
  if (kb0 + k0 + 8 <= R){
    *(u16x8*)dst = *(const u16x8*)&tile[d][k0];
  } else {
    #pragma unroll
    for (int e=0;e<8;++e) if (kb0 + k0 + e < R) dst[e] = tile[d][k0+e];
  }
}

// ---------------- fused rmsnorm + interleaved RoPE (bf16 in), bf16 head-major out ----
__global__ __launch_bounds__(256) void norm_rope_kernel(const unsigned short* __restrict__ lin,
    const float* __restrict__ g, const float* __restrict__ freqs, const int* __restrict__ cur,
    unsigned short* __restrict__ out, int S_, size_t head_stride, int row_off, float oscale){
  const int q = blockIdx.x, t = threadIdx.x;
  u16x8 v = *(const u16x8*)(lin + (size_t)q*DIMN + t*8);
  float x[8];
  #pragma unroll
  for (int e=0;e<8;++e) x[e] = bf2f(v[e]);
  float ss = 0.f;
  #pragma unroll
  for (int e=0;e<8;++e) ss += x[e]*x[e];
  for (int m=1;m<64;m<<=1) ss += __shfl_xor(ss, m);
  __shared__ float red[4];
  if ((t & 63) == 0) red[t>>6] = ss;
  __syncthreads();
  const float tot = red[0]+red[1]+red[2]+red[3];
  const float rstd = rsqrtf(tot * (1.0f/2048.0f) + 1e-6f);
  const int n0 = t*8;
  float xr[8];
  #pragma unroll
  for (int e=0;e<8;++e) xr[e] = x[e] * rstd * g[n0+e];
  const int pos = cur[0] + q;
  const int hh = n0 >> 7, d0 = n0 & 127;
  const float* fr = freqs + (size_t)pos * HDIM;
  float o[8];
  #pragma unroll
  for (int p=0;p<4;++p){
    const int j = (d0>>1) + p;
    const float c = fr[j], s = fr[64+j];
    o[2*p]   = xr[2*p]*c - xr[2*p+1]*s;
    o[2*p+1] = xr[2*p+1]*c + xr[2*p]*s;
  }
  u16x8 ov;
  #pragma unroll
  for (int e=0;e<8;++e) ov[e] = f2bf(o[e]*oscale);
  *(u16x8*)(out + (size_t)hh*head_stride + (size_t)(q+row_off)*HDIM + d0) = ov;
}

// ---------------- C[M,N] = A[M,K] * B[N,K]^T + bias, bf16 in fp32 out ----------------
__global__ __launch_bounds__(256,2) void gemm_bt(const unsigned short* __restrict__ A,
    const unsigned short* __restrict__ B, const float* __restrict__ bias,
    float* __restrict__ C, int M, int N, int K){
  __shared__ __align__(16) unsigned short As[128*64];
  __shared__ __align__(16) unsigned short Bs[128*64];
  const int t = threadIdx.x;
  const int w = t >> 6, lane = t & 63, lh = lane >> 4, ll = lane & 15;
  const int wr = w >> 1, wc = w & 1;
  const int m0 = blockIdx.y * 128, n0 = blockIdx.x * 128;
  const int srow = t >> 3;
  const int scb  = (t & 7) * 16;
  const int swc  = (scb ^ ((srow & 7) << 4)) >> 1;
  int arow[4]; size_t brow[4];
  #pragma unroll
  for (int c=0;c<4;++c){
    int r = m0 + c*32 + srow; if (r >= M) r = M-1;
    arow[c] = r;
    brow[c] = (size_t)(n0 + c*32 + srow);
  }
  const int xsw = (ll & 7) << 4;
  f32x4 acc[4][4] = {};
  const int nk = K >> 6;
  for (int kt = 0; kt < nk; ++kt){
    const int k0 = kt << 6;
    #pragma unroll
    for (int c=0;c<4;++c){
      gl_lds16(A + (size_t)arow[c]*K + k0 + swc, (char*)As + c*4096 + w*1024);
      gl_lds16(B + brow[c]*K       + k0 + swc, (char*)Bs + c*4096 + w*1024);
    }
    asm volatile("s_waitcnt vmcnt(0)" ::: "memory");
    __syncthreads();
    #pragma unroll
    for (int kk=0;kk<2;++kk){
      const int cb = kk*64 + lh*16;
      bfx8 a[4], b[4];
      #pragma unroll
      for (int i=0;i<4;++i)
        a[i] = *(const bfx8*)((const char*)As + (wr*64 + i*16 + ll)*128 + (cb ^ xsw));
      #pragma unroll
      for (int j=0;j<4;++j)
        b[j] = *(const bfx8*)((const char*)Bs + (wc*64 + j*16 + ll)*128 + (cb ^ xsw));
      #pragma unroll
      for (int i=0;i<4;++i)
        #pragma unroll
        for (int j=0;j<4;++j)
          acc[i][j] = MFMA16(a[i], b[j], acc[i][j]);
    }
    __syncthreads();
  }
  #pragma unroll
  for (int i=0;i<4;++i){
    #pragma unroll
    for (int j=0;j<4;++j){
      const int col = n0 + wc*64 + j*16 + ll;
      const float bb = bias[col];
      #pragma unroll
      for (int r=0;r<4;++r){
        const int row = m0 + wr*64 + i*16 + lh*4 + r;
        if (row < M) C[(size_t)row*N + col] = acc[i][j][r] + bb;
      }
    }
  }
}

// ---------------- fused QKV gemm: z selects weight/bias/output; bf16 out ----------------
__global__ __launch_bounds__(256,2) void gemm_qkv(const unsigned short* __restrict__ A,
    const unsigned short* __restrict__ B0, const unsigned short* __restrict__ B1,
    const unsigned short* __restrict__ B2, const float* __restrict__ g0,
    const float* __restrict__ g1, const float* __restrict__ g2,
    unsigned short* __restrict__ C0, unsigned short* __restrict__ C1,
    unsigned short* __restrict__ C2, int M, int N, int K){
  const int zz = blockIdx.z;
  const unsigned short* B = (zz==0) ? B0 : (zz==1) ? B1 : B2;
  const float* bias       = (zz==0) ? g0 : (zz==1) ? g1 : g2;
  unsigned short* C       = (zz==0) ? C0 : (zz==1) ? C1 : C2;
  __shared__ __align__(16) unsigned short As[128*64];
  __shared__ __align__(16) unsigned short Bs[128*64];
  const int t = threadIdx.x;
  const int w = t >> 6, lane = t & 63, lh = lane >> 4, ll = lane & 15;
  const int wr = w >> 1, wc = w & 1;
  const int m0 = blockIdx.y * 128, n0 = blockIdx.x * 128;
  const int srow = t >> 3;
  const int scb  = (t & 7) * 16;
  const int swc  = (scb ^ ((srow & 7) << 4)) >> 1;
  int arow[4]; size_t brow[4];
  #pragma unroll
  for (int c=0;c<4;++c){
    int r = m0 + c*32 + srow; if (r >= M) r = M-1;
    arow[c] = r;
    brow[c] = (size_t)(n0 + c*32 + srow);
  }
  const int xsw = (ll & 7) << 4;
  f32x4 acc[4][4] = {};
  const int nk = K >> 6;
  for (int kt = 0; kt < nk; ++kt){
    const int k0 = kt << 6;
    #pragma unroll
    for (int c=0;c<4;++c){
      gl_lds16(A + (size_t)arow[c]*K + k0 + swc, (char*)As + c*4096 + w*1024);
      gl_lds16(B + brow[c]*K       + k0 + swc, (char*)Bs + c*4096 + w*1024);
    }
    asm volatile("s_waitcnt vmcnt(0)" ::: "memory");
    __syncthreads();
    #pragma unroll
    for (int kk=0;kk<2;++kk){
      const int cb = kk*64 + lh*16;
      bfx8 a[4], b[4];
      #pragma unroll
      for (int i=0;i<4;++i)
        a[i] = *(const bfx8*)((const char*)As + (wr*64 + i*16 + ll)*128 + (cb ^ xsw));
      #pragma unroll
      for (int j=0;j<4;++j)
        b[j] = *(const bfx8*)((const char*)Bs + (wc*64 + j*16 + ll)*128 + (cb ^ xsw));
      #pragma unroll
      for (int i=0;i<4;++i)
        #pragma unroll
        for (int j=0;j<4;++j)
          acc[i][j] = MFMA16(a[i], b[j], acc[i][j]);
    }
    __syncthreads();
  }
  #pragma unroll
  for (int i=0;i<4;++i){
    #pragma unroll
    for (int j=0;j<4;++j){
      const int col = n0 + wc*64 + j*16 + ll;
      const float bb = bias[col];
      #pragma unroll
      for (int r=0;r<4;++r){
        const int row = m0 + wr*64 + i*16 + lh*4 + r;
        if (row < M) C[(size_t)row*N + col] = f2bf(acc[i][j][r] + bb);
      }
    }
  }
}

// ---------------- flash attention: 8 waves (512 thr), 16 q-rows/wave, dbuf LDS ----------
// 128 q-rows/block, 64-key tiles, KV-split via z, XCD-chunked swizzle (T1).
// Per-wave state halved vs 4-wave version: qf 16 + acc 32 + sc 16 regs -> ~110 live,
// launch_bounds(512,4) caps at 128 (4 waves/SIMD, 2 blocks/CU; LDS exactly 80KB).
// Swapped QK^T (lane owns q-row=ll), exp2-domain softmax (scale*log2e in Q),
// R6-proven one-barrier double-buffer schedule.
__global__ __launch_bounds__(512,4) void attn_kernel(const unsigned short* __restrict__ Q,
    const unsigned short* __restrict__ K, const unsigned short* __restrict__ VT,
    unsigned short* __restrict__ O, float* __restrict__ pacc, float* __restrict__ pml,
    int S_, int L_, int CLn, int nx, int nsplit){
  __shared__ __align__(16) unsigned short Ks[2][64*128];
  __shared__ __align__(16) unsigned short Vs[2][128*64];
  __shared__ __align__(16) unsigned short Ps[8][16*64];
  const int nwg = gridDim.x;
  const int swzid = (blockIdx.x & 7)*(nwg >> 3) + (blockIdx.x >> 3);
  const int xq = swzid % nx;
  const int rest = swzid / nx;
  const int hh = rest % NH;
  const int z  = rest / NH;
  const int q0 = xq * 128;
  const int t = threadIdx.x, w = t >> 6, lane = t & 63, lh = lane >> 4, ll = lane & 15;
  const int xsw = (ll & 7) << 4;
  char* Pw = (char*)Ps[w];
  const unsigned short* Qh = Q  + (size_t)hh*S_*HDIM;
  const unsigned short* Kh = K  + (size_t)hh*L_*HDIM;
  const unsigned short* Vh = VT + (size_t)hh*HDIM*L_;
  const int wrow0 = q0 + w*16;            // 16 q-rows per wave
  bfx8 qf[4];
  {
    int qr = wrow0 + ll; if (qr >= S_) qr = S_ - 1;
    #pragma unroll
    for (int kk=0;kk<4;++kk)
      qf[kk] = *(const bfx8*)(Qh + (size_t)qr*HDIM + kk*32 + lh*8);
  }
  f32x4 acc[8] = {};
  float m_st = -1e20f, l_st = 0.f;
  int qlast = q0 + 127; if (qlast >= S_) qlast = S_ - 1;
  const int kend = CLn + qlast + 1;
  const int nt = (kend + 63) >> 6;
  const int tps = (nt + nsplit - 1) / nsplit;
  const int t0 = z * tps;
  int t1 = t0 + tps; if (t1 > nt) t1 = nt;
  const int ksrow = t >> 4, kchunk = t & 15;   // K tile: 64 rows x 256B, 2 chunks/thread
  const int vsrow = t >> 3, vchunk = t & 7;    // V tile: 128 rows x 128B, 2 chunks/thread
  const int myq = wrow0 + ll;
  const int last = nt - 1;

  u16x8 kreg[2], vreg[2];
  auto load_tile = [&](int ktile){
    const int kv0 = ktile << 6;
    if (ktile == last){
      #pragma unroll
      for (int c=0;c<2;++c){
        int krow = kv0 + c*32 + ksrow; if (krow >= L_) krow = L_ - 1;
        kreg[c] = *(const u16x8*)(Kh + (size_t)krow*HDIM + kchunk*8);
      }
      int vcol = kv0 + vchunk*8; if (vcol > L_ - 8) vcol = L_ - 8;
      #pragma unroll
      for (int c=0;c<2;++c)
        vreg[c] = *(const u16x8*)(Vh + (size_t)(c*64 + vsrow)*L_ + vcol);
    } else {
      #pragma unroll
      for (int c=0;c<2;++c)
        kreg[c] = *(const u16x8*)(Kh + (size_t)(kv0 + c*32 + ksrow)*HDIM + kchunk*8);
      const int vcol = kv0 + vchunk*8;
      #pragma unroll
      for (int c=0;c<2;++c)
        vreg[c] = *(const u16x8*)(Vh + (size_t)(c*64 + vsrow)*L_ + vcol);
    }
  };
  auto stage_write = [&](int b){
    #pragma unroll
    for (int c=0;c<2;++c)
      *(u16x8*)((char*)Ks[b] + (c*32 + ksrow)*256 + ((kchunk*16) ^ ((ksrow & 7) << 4))) = kreg[c];
    #pragma unroll
    for (int c=0;c<2;++c)
      *(u16x8*)((char*)Vs[b] + (c*64 + vsrow)*128 + ((vchunk*16) ^ ((vsrow & 7) << 4))) = vreg[c];
  };

  if (t0 < t1){
    load_tile(t0);
    stage_write(0);
    if (t0 + 1 < t1) load_tile(t0 + 1);
  }
  int cur = 0;
  for (int kt = t0; kt < t1; ++kt){
    const int kv0 = kt << 6;
    __syncthreads();   // buf[cur] visible; all waves done with buf[cur^1]
    const char* Kc = (const char*)Ks[cur];
    const char* Vc = (const char*)Vs[cur];
    // QK^T (swapped): C[row=k_sub][col=q=ll], pre-scaled to exp2 domain
    f32x4 sc[4] = {};
    #pragma unroll
    for (int kk=0;kk<4;++kk){
      const int cb = kk*64 + lh*16;
      #pragma unroll
      for (int j=0;j<4;++j){
        bfx8 kf = *(const bfx8*)(Kc + (j*16 + ll)*256 + (cb ^ xsw));
        sc[j] = MFMA16(kf, qf[kk], sc[j]);
      }
    }
    if (kt + 1 < t1){
      stage_write(cur ^ 1);
      if (kt + 2 < t1) load_tile(kt + 2);
    }
    // causal mask
    if (kv0 + 63 > CLn + wrow0){
      const int lim = CLn + myq;
      #pragma unroll
      for (int j=0;j<4;++j)
        #pragma unroll
        for (int r=0;r<4;++r){
          const int key = kv0 + j*16 + lh*4 + r;
          if (key > lim) sc[j][r] = -1e30f;
        }
    }
    // row max: in-lane 16 + cross-replica
    float mt = sc[0][0];
    #pragma unroll
    for (int j=0;j<4;++j)
      #pragma unroll
      for (int r=0;r<4;++r) mt = fmaxf(mt, sc[j][r]);
    mt = fmaxf(mt, __shfl_xor(mt, 16));
    mt = fmaxf(mt, __shfl_xor(mt, 32));
    mt = fmaxf(mt, -1e20f);
    if (!__all(mt - m_st <= 11.54f)){   // defer-max (8 nats in log2 domain)
      const float mn = fmaxf(m_st, mt);
      const float corr = exp2f(m_st - mn);
      m_st = mn;
      l_st *= corr;
      #pragma unroll
      for (int r=0;r<4;++r){
        const float ca = __shfl(corr, lh*4 + r);
        #pragma unroll
        for (int jn=0;jn<8;++jn) acc[jn][r] *= ca;
      }
    }
    // P = exp2(sc - m), row sum
    float rs = 0.f;
    #pragma unroll
    for (int j=0;j<4;++j)
      #pragma unroll
      for (int r=0;r<4;++r){
        const float pv = exp2f(sc[j][r] - m_st);
        sc[j][r] = pv;
        rs += pv;
      }
    rs += __shfl_xor(rs, 16);
    rs += __shfl_xor(rs, 32);
    l_st += rs;
    // P-store (wave-private; compiler pairs (__bf16) casts into v_cvt_pk_bf16_f32)
    #pragma unroll
    for (int j=0;j<4;++j){
      bf16x4 pk = { (__bf16)sc[j][0], (__bf16)sc[j][1], (__bf16)sc[j][2], (__bf16)sc[j][3] };
      *(bf16x4*)(Pw + ll*128 + ((j*32 + lh*8) ^ xsw)) = pk;
    }
    // PV
    #pragma unroll
    for (int kk=0;kk<2;++kk){
      const int cb = kk*64 + lh*16;
      bfx8 af = *(const bfx8*)(Pw + ll*128 + (cb ^ xsw));
      #pragma unroll
      for (int jn=0;jn<8;++jn){
        bfx8 vf = *(const bfx8*)(Vc + (jn*16 + ll)*128 + (cb ^ xsw));
        acc[jn] = MFMA16(af, vf, acc[jn]);
      }
    }
    cur ^= 1;
  }
  // epilogue
  if (nsplit == 1){
    const float linv = 1.0f / l_st;
    #pragma unroll
    for (int r=0;r<4;++r){
      const float inv = __shfl(linv, lh*4 + r);
      const int qr = wrow0 + lh*4 + r;
      if (qr < S_){
        #pragma unroll
        for (int jn=0;jn<8;++jn)
          O[(size_t)qr*DIMN + hh*HDIM + jn*16 + ll] = f2bf(acc[jn][r]*inv);
      }
    }
  } else {
    #pragma unroll
    for (int r=0;r<4;++r){
      const int qr = wrow0 + lh*4 + r;
      if (qr < S_){
        const size_t rid = ((size_t)z*NH + hh)*S_ + qr;
        float* dst = pacc + rid*128;
        #pragma unroll
        for (int jn=0;jn<8;++jn) dst[jn*16 + ll] = acc[jn][r];
      }
    }
    if (lane < 16){
      if (myq < S_){
        const size_t rid2 = ((size_t)z*NH + hh)*S_ + myq;
        pml[rid2*2]   = m_st;
        pml[rid2*2+1] = l_st;
      }
    }
  }
}

// ---------------- combine partials -> ob bf16 (exp2 domain m) ----------------
__global__ __launch_bounds__(256) void combine_kernel(const float* __restrict__ pacc,
    const float* __restrict__ pml, unsigned short* __restrict__ ob, int S_, int nsplit){
  const int t = threadIdx.x;
  const int rid = blockIdx.x*2 + (t >> 7);   // hh*S_+q
  if (rid >= S_*NH) return;
  const int d = t & 127;
  const int hh = rid / S_;
  const int q  = rid - hh*S_;
  float M = -1e20f;
  for (int s=0; s<nsplit; ++s)
    M = fmaxf(M, pml[((size_t)s*NH*S_ + rid)*2]);
  float lt = 0.f, o = 0.f;
  for (int s=0; s<nsplit; ++s){
    const float m = pml[((size_t)s*NH*S_ + rid)*2];
    const float l = pml[((size_t)s*NH*S_ + rid)*2 + 1];
    const float wgt = exp2f(m - M);
    lt += l * wgt;
    o  += pacc[((size_t)s*NH*S_ + rid)*128 + d] * wgt;
  }
  if (lt == 0.f) lt = 1.f;
  ob[(size_t)q*DIMN + hh*HDIM + d] = f2bf(o / lt);
}

extern "C" void kernel_launch(void* const* d_in, const int* in_sizes, int n_in,
                              void* d_out, int out_size, void* d_ws, size_t ws_size,
                              hipStream_t stream){
  const float* x       = (const float*)d_in[0];
  const float* freqs   = (const float*)d_in[1];
  const float* k_cache = (const float*)d_in[2];
  const float* v_cache = (const float*)d_in[3];
  const float* Wq = (const float*)d_in[4];
  const float* bq = (const float*)d_in[5];
  const float* Wk = (const float*)d_in[6];
  const float* bk = (const float*)d_in[7];
  const float* Wv = (const float*)d_in[8];
  const float* bv = (const float*)d_in[9];
  const float* Wo = (const float*)d_in[10];
  const float* bo = (const float*)d_in[11];
  const float* gq = (const float*)d_in[12];
  const float* gk = (const float*)d_in[13];
  const int*   cur = (const int*)d_in[14];

  const int S = in_sizes[0] / DIMN;
  const int CACHE_ = in_sizes[2] / DIMN;
  const int L = CACHE_ + S;
  const int CLn = L - S;

  auto al = [](size_t n){ return (n + 255) & ~(size_t)255; };
  char* base = (char*)d_ws;
  size_t off = 0;
  auto take = [&](size_t n){ char* r = base + off; off += al(n); return r; };
  // persistent:
  unsigned short* xb  = (unsigned short*)take((size_t)S*DIMN*2);
  unsigned short* Wob = (unsigned short*)take((size_t)DIMN*DIMN*2);
  unsigned short* qb  = (unsigned short*)take((size_t)NH*S*HDIM*2);
  unsigned short* kb  = (unsigned short*)take((size_t)NH*L*HDIM*2);
  unsigned short* vtb = (unsigned short*)take((size_t)NH*HDIM*L*2);
  unsigned short* ob  = (unsigned short*)take((size_t)S*DIMN*2);
  const size_t ubase = off;
  // union pool A: transients (dead before attn): lin0/1/2 (bf16) + Wq/Wk/Wv (bf16)
  const size_t l_sz = al((size_t)S*DIMN*2);
  const size_t w_sz = al((size_t)DIMN*DIMN*2);
  unsigned short* lin0 = (unsigned short*)(base + ubase);
  unsigned short* lin1 = (unsigned short*)(base + ubase + l_sz);
  unsigned short* lin2 = (unsigned short*)(base + ubase + 2*l_sz);
  unsigned short* Wqb  = (unsigned short*)(base + ubase + 3*l_sz);
  unsigned short* Wkb  = (unsigned short*)(base + ubase + 3*l_sz + w_sz);
  unsigned short* Wvb  = (unsigned short*)(base + ubase + 3*l_sz + 2*w_sz);
  const size_t trans_sz = 3*l_sz + 3*w_sz;
  // union pool B: attention partials
  auto pool_sz = [&](int ns){
    return al((size_t)ns*NH*S*HDIM*4) + al((size_t)ns*NH*S*2*4);
  };
  int nsplit = 1;
  if (ubase + (trans_sz > pool_sz(4) ? trans_sz : pool_sz(4)) <= ws_size) nsplit = 4;
  else if (ubase + (trans_sz > pool_sz(2) ? trans_sz : pool_sz(2)) <= ws_size) nsplit = 2;
  if (ubase + trans_sz > ws_size) return;
  float* pacc = (float*)(base + ubase);
  float* pml  = (float*)(base + ubase + al((size_t)nsplit*NH*S*HDIM*4));

  const int wn8 = DIMN*DIMN/8;
  cast_bf16_kernel<<<(S*DIMN/8+255)/256, 256, 0, stream>>>(x,  xb,  S*DIMN/8);
  cast_bf16_kernel<<<(wn8+255)/256, 256, 0, stream>>>(Wq, Wqb, wn8);
  cast_bf16_kernel<<<(wn8+255)/256, 256, 0, stream>>>(Wk, Wkb, wn8);
  cast_bf16_kernel<<<(wn8+255)/256, 256, 0, stream>>>(Wv, Wvb, wn8);
  cast_bf16_kernel<<<(wn8+255)/256, 256, 0, stream>>>(Wo, Wob, wn8);
  kcache_kernel<<<CACHE_, 256, 0, stream>>>(k_cache, kb, CACHE_, L);
  vtrans_kernel<<<dim3((CACHE_+63)/64, 4, NH), 256, 0, stream>>>(v_cache, vtb, CACHE_, 0, L);

  const int mb = (S+127)/128;
  gemm_qkv<<<dim3(DIMN/128, mb, 3), 256, 0, stream>>>(xb, Wqb, Wkb, Wvb, bq, bk, bv,
                                                      lin0, lin1, lin2, S, DIMN, DIMN);
  const float qsc = 0.08838834764831845f * 1.4426950408889634f;
  norm_rope_kernel<<<S, 256, 0, stream>>>(lin0, gq, freqs, cur, qb, S, (size_t)S*HDIM, 0, qsc);
  norm_rope_kernel<<<S, 256, 0, stream>>>(lin1, gk, freqs, cur, kb, S, (size_t)L*HDIM, CACHE_, 1.0f);
  vtrans_bf16_kernel<<<dim3((S+63)/64, 4, NH), 256, 0, stream>>>(lin2, vtb, S, CACHE_, L);

  const int nx = (S+127)/128;
  attn_kernel<<<nx*NH*nsplit, 512, 0, stream>>>(qb, kb, vtb, ob,
                                                pacc, pml, S, L, CLn, nx, nsplit);
  if (nsplit > 1)
    combine_kernel<<<(S*NH+1)/2, 256, 0, stream>>>(pacc, pml, ob, S, nsplit);
  gemm_bt<<<dim3(DIMN/128, mb), 256, 0, stream>>>(ob, Wob, bo, (float*)d_out, S, DIMN, DIMN);
}

// Round 11
// 516.799 us; speedup vs baseline: 1.2757x; 1.0139x over previous
//
#include <hip/hip_runtime.h>

#define DIMN 2048
#define NH 16
#define HDIM 128

typedef __attribute__((ext_vector_type(4))) float f32x4;
typedef __attribute__((ext_vector_type(16))) float f32x16;
typedef __attribute__((ext_vector_type(8))) __bf16 bfx8;
typedef __attribute__((ext_vector_type(2))) __bf16 bf16x2;
typedef __attribute__((ext_vector_type(8))) unsigned short u16x8;

__device__ __forceinline__ unsigned short f2bf(float f){
  unsigned u = __builtin_bit_cast(unsigned, f);
  u += 0x7fffu + ((u >> 16) & 1u);
  return (unsigned short)(u >> 16);
}
__device__ __forceinline__ float bf2f(unsigned short h){
  unsigned u = (unsigned)h << 16;
  return __builtin_bit_cast(float, u);
}
__device__ __forceinline__ unsigned pk2(float a, float b){
  bf16x2 v = { (__bf16)a, (__bf16)b };       // compiler pairs into v_cvt_pk_bf16_f32
  return __builtin_bit_cast(unsigned, v);
}

__device__ __forceinline__ void gl_lds16(const void* g, void* l){
  __builtin_amdgcn_global_load_lds((const __attribute__((address_space(1))) void*)g,
                                   (__attribute__((address_space(3))) void*)l, 16, 0, 0);
}

#define MFMA16(a,b,c) __builtin_amdgcn_mfma_f32_16x16x32_bf16((a),(b),(c),0,0,0)
#define MFMA32(a,b,c) __builtin_amdgcn_mfma_f32_32x32x16_bf16((a),(b),(c),0,0,0)

// ---------------- elementwise f32 -> bf16 cast ----------------
__global__ __launch_bounds__(256) void cast_bf16_kernel(const float* __restrict__ in,
                                                        unsigned short* __restrict__ out, int n8){
  int i = blockIdx.x*256 + threadIdx.x;
  if (i >= n8) return;
  const float4* p = (const float4*)(in + (size_t)i*8);
  float4 a = p[0], b = p[1];
  u16x8 o;
  o[0]=f2bf(a.x); o[1]=f2bf(a.y); o[2]=f2bf(a.z); o[3]=f2bf(a.w);
  o[4]=f2bf(b.x); o[5]=f2bf(b.y); o[6]=f2bf(b.z); o[7]=f2bf(b.w);
  *(u16x8*)(out + (size_t)i*8) = o;
}

// ---------------- k_cache (CACHE,H,HD) f32 -> kb[h][k][d] bf16 ----------------
__global__ __launch_bounds__(256) void kcache_kernel(const float* __restrict__ kc,
                                                     unsigned short* __restrict__ kb,
                                                     int R, int L_){
  const int gid = blockIdx.x*256 + threadIdx.x;
  if (gid >= R*256) return;
  const size_t idx = (size_t)gid * 8;
  const int k   = (int)(idx >> 11);
  const int rem = (int)(idx & 2047);
  const int hh  = rem >> 7, d = rem & 127;
  const float4* p = (const float4*)(kc + idx);
  float4 a = p[0], b = p[1];
  u16x8 o;
  o[0]=f2bf(a.x); o[1]=f2bf(a.y); o[2]=f2bf(a.z); o[3]=f2bf(a.w);
  o[4]=f2bf(b.x); o[5]=f2bf(b.y); o[6]=f2bf(b.z); o[7]=f2bf(b.w);
  *(u16x8*)(kb + (size_t)hh*L_*HDIM + (size_t)k*HDIM + d) = o;
}

// ---------------- (R,H,HD) f32 -> vt[h][d][koff+k] bf16 (transpose) ----------------
__global__ __launch_bounds__(256) void vtrans_kernel(const float* __restrict__ src,
                                                     unsigned short* __restrict__ vt,
                                                     int R, int koff, int L_){
  __shared__ __align__(16) unsigned short tile[32][72];
  const int kb0 = blockIdx.x * 64, db0 = blockIdx.y * 32, hh = blockIdx.z;
  const int t = threadIdx.x;
  const int kk = t >> 2, dd = (t & 3) * 8;
  const int k = kb0 + kk;
  if (k < R){
    const float* p = src + (size_t)k*DIMN + hh*HDIM + db0 + dd;
    float4 a = ((const float4*)p)[0], b = ((const float4*)p)[1];
    tile[dd+0][kk] = f2bf(a.x); tile[dd+1][kk] = f2bf(a.y);
    tile[dd+2][kk] = f2bf(a.z); tile[dd+3][kk] = f2bf(a.w);
    tile[dd+4][kk] = f2bf(b.x); tile[dd+5][kk] = f2bf(b.y);
    tile[dd+6][kk] = f2bf(b.z); tile[dd+7][kk] = f2bf(b.w);
  }
  __syncthreads();
  const int d = t >> 3, k0 = (t & 7) * 8;
  unsigned short* dst = vt + (size_t)hh*HDIM*L_ + (size_t)(db0+d)*L_ + koff + kb0 + k0;
  if (kb0 + k0 + 8 <= R){
    *(u16x8*)dst = *(const u16x8*)&tile[d][k0];
  } else {
    #pragma unroll
    for (int e=0;e<8;++e) if (kb0 + k0 + e < R) dst[e] = tile[d][k0+e];
  }
}

// ---------------- same but bf16 source (projected V) ----------------
__global__ __launch_bounds__(256) void vtrans_bf16_kernel(const unsigned short* __restrict__ src,
    unsigned short* __restrict__ vt, int R, int koff, int L_){
  __shared__ __align__(16) unsigned short tile[32][72];
  const int kb0 = blockIdx.x * 64, db0 = blockIdx.y * 32, hh = blockIdx.z;
  const int t = threadIdx.x;
  const int kk = t >> 2, dd = (t & 3) * 8;
  const int k = kb0 + kk;
  if (k < R){
    u16x8 a = *(const u16x8*)(src + (size_t)k*DIMN + hh*HDIM + db0 + dd);
    #pragma unroll
    for (int e=0;e<8;++e) tile[dd+e][kk] = a[e];
  }
  __syncthreads();
  const int d = t >> 3, k0 = (t & 7) * 8;
  unsigned short* dst = vt + (size_t)hh*HDIM*L_ + (size_t)(db0+d)*L_ + koff + kb0 + k0;
  if (kb0 + k0 + 8 <= R){
    *(u16x8*)dst = *(const u16x8*)&tile[d][k0];
  } else {
    #pragma unroll
    for (int e=0;e<8;++e) if (kb0 + k0 + e < R) dst[e] = tile[d][k0+e];
  }
}

// ---------------- fused rmsnorm + interleaved RoPE (bf16 in), bf16 head-major out ----
__global__ __launch_bounds__(256) void norm_rope_kernel(const unsigned short* __restrict__ lin,
    const float* __restrict__ g, const float* __restrict__ freqs, const int* __restrict__ cur,
    unsigned short* __restrict__ out, int S_, size_t head_stride, int row_off, float oscale){
  const int q = blockIdx.x, t = threadIdx.x;
  u16x8 v = *(const u16x8*)(lin + (size_t)q*DIMN + t*8);
  float x[8];
  #pragma unroll
  for (int e=0;e<8;++e) x[e] = bf2f(v[e]);
  float ss = 0.f;
  #pragma unroll
  for (int e=0;e<8;++e) ss += x[e]*x[e];
  for (int m=1;m<64;m<<=1) ss += __shfl_xor(ss, m);
  __shared__ float red[4];
  if ((t & 63) == 0) red[t>>6] = ss;
  __syncthreads();
  const float tot = red[0]+red[1]+red[2]+red[3];
  const float rstd = rsqrtf(tot * (1.0f/2048.0f) + 1e-6f);
  const int n0 = t*8;
  float xr[8];
  #pragma unroll
  for (int e=0;e<8;++e) xr[e] = x[e] * rstd * g[n0+e];
  const int pos = cur[0] + q;
  const int hh = n0 >> 7, d0 = n0 & 127;
  const float* fr = freqs + (size_t)pos * HDIM;
  float o[8];
  #pragma unroll
  for (int p=0;p<4;++p){
    const int j = (d0>>1) + p;
    const float c = fr[j], s = fr[64+j];
    o[2*p]   = xr[2*p]*c - xr[2*p+1]*s;
    o[2*p+1] = xr[2*p+1]*c + xr[2*p]*s;
  }
  u16x8 ov;
  #pragma unroll
  for (int e=0;e<8;++e) ov[e] = f2bf(o[e]*oscale);
  *(u16x8*)(out + (size_t)hh*head_stride + (size_t)(q+row_off)*HDIM + d0) = ov;
}

// ---------------- C[M,N] = A[M,K] * B[N,K]^T + bias, bf16 in fp32 out ----------------
__global__ __launch_bounds__(256,2) void gemm_bt(const unsigned short* __restrict__ A,
    const unsigned short* __restrict__ B, const float* __restrict__ bias,
    float* __restrict__ C, int M, int N, int K){
  __shared__ __align__(16) unsigned short As[128*64];
  __shared__ __align__(16) unsigned short Bs[128*64];
  const int t = threadIdx.x;
  const int w = t >> 6, lane = t & 63, lh = lane >> 4, ll = lane & 15;
  const int wr = w >> 1, wc = w & 1;
  const int m0 = blockIdx.y * 128, n0 = blockIdx.x * 128;
  const int srow = t >> 3;
  const int scb  = (t & 7) * 16;
  const int swc  = (scb ^ ((srow & 7) << 4)) >> 1;
  int arow[4]; size_t brow[4];
  #pragma unroll
  for (int c=0;c<4;++c){
    int r = m0 + c*32 + srow; if (r >= M) r = M-1;
    arow[c] = r;
    brow[c] = (size_t)(n0 + c*32 + srow);
  }
  const int xsw = (ll & 7) << 4;
  f32x4 acc[4][4] = {};
  const int nk = K >> 6;
  for (int kt = 0; kt < nk; ++kt){
    const int k0 = kt << 6;
    #pragma unroll
    for (int c=0;c<4;++c){
      gl_lds16(A + (size_t)arow[c]*K + k0 + swc, (char*)As + c*4096 + w*1024);
      gl_lds16(B + brow[c]*K       + k0 + swc, (char*)Bs + c*4096 + w*1024);
    }
    asm volatile("s_waitcnt vmcnt(0)" ::: "memory");
    __syncthreads();
    #pragma unroll
    for (int kk=0;kk<2;++kk){
      const int cb = kk*64 + lh*16;
      bfx8 a[4], b[4];
      #pragma unroll
      for (int i=0;i<4;++i)
        a[i] = *(const bfx8*)((const char*)As + (wr*64 + i*16 + ll)*128 + (cb ^ xsw));
      #pragma unroll
      for (int j=0;j<4;++j)
        b[j] = *(const bfx8*)((const char*)Bs + (wc*64 + j*16 + ll)*128 + (cb ^ xsw));
      #pragma unroll
      for (int i=0;i<4;++i)
        #pragma unroll
        for (int j=0;j<4;++j)
          acc[i][j] = MFMA16(a[i], b[j], acc[i][j]);
    }
    __syncthreads();
  }
  #pragma unroll
  for (int i=0;i<4;++i){
    #pragma unroll
    for (int j=0;j<4;++j){
      const int col = n0 + wc*64 + j*16 + ll;
      const float bb = bias[col];
      #pragma unroll
      for (int r=0;r<4;++r){
        const int row = m0 + wr*64 + i*16 + lh*4 + r;
        if (row < M) C[(size_t)row*N + col] = acc[i][j][r] + bb;
      }
    }
  }
}

// ---------------- fused QKV gemm: z selects weight/bias/output; bf16 out ----------------
__global__ __launch_bounds__(256,2) void gemm_qkv(const unsigned short* __restrict__ A,
    const unsigned short* __restrict__ B0, const unsigned short* __restrict__ B1,
    const unsigned short* __restrict__ B2, const float* __restrict__ g0,
    const float* __restrict__ g1, const float* __restrict__ g2,
    unsigned short* __restrict__ C0, unsigned short* __restrict__ C1,
    unsigned short* __restrict__ C2, int M, int N, int K){
  const int zz = blockIdx.z;
  const unsigned short* B = (zz==0) ? B0 : (zz==1) ? B1 : B2;
  const float* bias       = (zz==0) ? g0 : (zz==1) ? g1 : g2;
  unsigned short* C       = (zz==0) ? C0 : (zz==1) ? C1 : C2;
  __shared__ __align__(16) unsigned short As[128*64];
  __shared__ __align__(16) unsigned short Bs[128*64];
  const int t = threadIdx.x;
  const int w = t >> 6, lane = t & 63, lh = lane >> 4, ll = lane & 15;
  const int wr = w >> 1, wc = w & 1;
  const int m0 = blockIdx.y * 128, n0 = blockIdx.x * 128;
  const int srow = t >> 3;
  const int scb  = (t & 7) * 16;
  const int swc  = (scb ^ ((srow & 7) << 4)) >> 1;
  int arow[4]; size_t brow[4];
  #pragma unroll
  for (int c=0;c<4;++c){
    int r = m0 + c*32 + srow; if (r >= M) r = M-1;
    arow[c] = r;
    brow[c] = (size_t)(n0 + c*32 + srow);
  }
  const int xsw = (ll & 7) << 4;
  f32x4 acc[4][4] = {};
  const int nk = K >> 6;
  for (int kt = 0; kt < nk; ++kt){
    const int k0 = kt << 6;
    #pragma unroll
    for (int c=0;c<4;++c){
      gl_lds16(A + (size_t)arow[c]*K + k0 + swc, (char*)As + c*4096 + w*1024);
      gl_lds16(B + brow[c]*K       + k0 + swc, (char*)Bs + c*4096 + w*1024);
    }
    asm volatile("s_waitcnt vmcnt(0)" ::: "memory");
    __syncthreads();
    #pragma unroll
    for (int kk=0;kk<2;++kk){
      const int cb = kk*64 + lh*16;
      bfx8 a[4], b[4];
      #pragma unroll
      for (int i=0;i<4;++i)
        a[i] = *(const bfx8*)((const char*)As + (wr*64 + i*16 + ll)*128 + (cb ^ xsw));
      #pragma unroll
      for (int j=0;j<4;++j)
        b[j] = *(const bfx8*)((const char*)Bs + (wc*64 + j*16 + ll)*128 + (cb ^ xsw));
      #pragma unroll
      for (int i=0;i<4;++i)
        #pragma unroll
        for (int j=0;j<4;++j)
          acc[i][j] = MFMA16(a[i], b[j], acc[i][j]);
    }
    __syncthreads();
  }
  #pragma unroll
  for (int i=0;i<4;++i){
    #pragma unroll
    for (int j=0;j<4;++j){
      const int col = n0 + wc*64 + j*16 + ll;
      const float bb = bias[col];
      #pragma unroll
      for (int r=0;r<4;++r){
        const int row = m0 + wr*64 + i*16 + lh*4 + r;
        if (row < M) C[(size_t)row*N + col] = f2bf(acc[i][j][r] + bb);
      }
    }
  }
}

// ---------------- flash attention: 4 waves, 32x32x16 MFMA, P via LDS ----------------
// 128 q-rows/block (32/wave), 64-key tiles, KV-split via z, XCD swizzle (T1).
// Swapped QK^T via mfma_32x32x16: D[k][q], col=lane&31=q (lane owns ONE q-row),
// row=(reg&3)+8*(reg>>2)+4*(lane>>5). Softmax: 31 in-lane fmax + 1 shfl_xor(32).
// P transport: D-layout packed-u32 writes into wave-private swizzled LDS, A-frag
// read back as 4 contiguous ds_read_b128 (R5/R6/R7-proven transport; replaces
// R10's permlane32_swap whose lane-half direction could not be verified).
__global__ __launch_bounds__(256,2) void attn_kernel(const unsigned short* __restrict__ Q,
    const unsigned short* __restrict__ K, const unsigned short* __restrict__ VT,
    unsigned short* __restrict__ O, float* __restrict__ pacc, float* __restrict__ pml,
    int S_, int L_, int CLn, int nx, int nsplit){
  __shared__ __align__(16) unsigned short Ks[2][64*128];
  __shared__ __align__(16) unsigned short Vs[2][128*64];
  __shared__ __align__(16) unsigned short Ps[4][32*64];
  const int nwg = gridDim.x;
  const int swzid = (blockIdx.x & 7)*(nwg >> 3) + (blockIdx.x >> 3);
  const int xq = swzid % nx;
  const int rest = swzid / nx;
  const int hh = rest % NH;
  const int z  = rest / NH;
  const int q0 = xq * 128;
  const int t = threadIdx.x, w = t >> 6, lane = t & 63;
  const int l31 = lane & 31, h = lane >> 5;
  char* Pw = (char*)Ps[w];
  const int xswp = (l31 & 7) << 4;
  const unsigned short* Qh = Q  + (size_t)hh*S_*HDIM;
  const unsigned short* Kh = K  + (size_t)hh*L_*HDIM;
  const unsigned short* Vh = VT + (size_t)hh*HDIM*L_;
  const int wrow0 = q0 + w*32;
  const int myq = wrow0 + l31;            // this lane's q-row (state + QK^T col)
  // Q fragment (B-operand of 32x32x16): lane holds Q[myq][kk*16 + h*8 .. +7]
  bfx8 qf[8];
  {
    int qr = myq; if (qr >= S_) qr = S_ - 1;
    #pragma unroll
    for (int kk=0;kk<8;++kk)
      qf[kk] = *(const bfx8*)(Qh + (size_t)qr*HDIM + kk*16 + h*8);
  }
  f32x16 acc[4] = {};                     // [db]: O[q(reg,h)][db*32 + l31]
  float m_st = -1e20f, l_st = 0.f;
  int qlast = q0 + 127; if (qlast >= S_) qlast = S_ - 1;
  const int kend = CLn + qlast + 1;
  const int nt = (kend + 63) >> 6;
  const int tps = (nt + nsplit - 1) / nsplit;
  const int t0 = z * tps;
  int t1 = t0 + tps; if (t1 > nt) t1 = nt;
  const int ksrow = t >> 4, kchunk = t & 15;
  const int vsrow = t >> 3, vchunk = t & 7;
  const int last = nt - 1;

  u16x8 kreg[4], vreg[4];
  auto load_tile = [&](int ktile){
    const int kv0 = ktile << 6;
    if (ktile == last){
      #pragma unroll
      for (int c=0;c<4;++c){
        int krow = kv0 + c*16 + ksrow; if (krow >= L_) krow = L_ - 1;
        kreg[c] = *(const u16x8*)(Kh + (size_t)krow*HDIM + kchunk*8);
      }
      int vcol = kv0 + vchunk*8; if (vcol > L_ - 8) vcol = L_ - 8;
      #pragma unroll
      for (int c=0;c<4;++c)
        vreg[c] = *(const u16x8*)(Vh + (size_t)(c*32 + vsrow)*L_ + vcol);
    } else {
      #pragma unroll
      for (int c=0;c<4;++c)
        kreg[c] = *(const u16x8*)(Kh + (size_t)(kv0 + c*16 + ksrow)*HDIM + kchunk*8);
      const int vcol = kv0 + vchunk*8;
      #pragma unroll
      for (int c=0;c<4;++c)
        vreg[c] = *(const u16x8*)(Vh + (size_t)(c*32 + vsrow)*L_ + vcol);
    }
  };
  auto stage_write = [&](int b){
    #pragma unroll
    for (int c=0;c<4;++c)
      *(u16x8*)((char*)Ks[b] + (c*16 + ksrow)*256 + ((kchunk*16) ^ ((ksrow & 7) << 4))) = kreg[c];
    #pragma unroll
    for (int c=0;c<4;++c)
      *(u16x8*)((char*)Vs[b] + (c*32 + vsrow)*128 + ((vchunk*16) ^ ((vsrow & 7) << 4))) = vreg[c];
  };

  if (t0 < t1){
    load_tile(t0);
    stage_write(0);
    if (t0 + 1 < t1) load_tile(t0 + 1);
  }
  const int krow0 = l31,      koff0 = (krow0 & 7) << 4;   // j=0 K rows
  const int krow1 = 32 + l31, koff1 = (krow1 & 7) << 4;   // j=1 K rows
  int cur = 0;
  for (int kt = t0; kt < t1; ++kt){
    const int kv0 = kt << 6;
    __syncthreads();   // buf[cur] visible; all waves done with buf[cur^1]
    const char* Kc = (const char*)Ks[cur];
    const char* Vc = (const char*)Vs[cur];
    // QK^T: sc_j[reg] = S[k = kv0 + 32j + (reg&3)+8*(reg>>2)+4h][q = myq]
    f32x16 sc0 = {}, sc1 = {};
    #pragma unroll
    for (int kk=0;kk<8;++kk){
      const int cb = kk*32 + h*16;
      bfx8 kf0 = *(const bfx8*)(Kc + krow0*256 + (cb ^ koff0));
      bfx8 kf1 = *(const bfx8*)(Kc + krow1*256 + (cb ^ koff1));
      sc0 = MFMA32(kf0, qf[kk], sc0);
      sc1 = MFMA32(kf1, qf[kk], sc1);
    }
    if (kt + 1 < t1){
      stage_write(cur ^ 1);
      if (kt + 2 < t1) load_tile(kt + 2);
    }
    // causal mask (scale*log2e folded into Q)
    if (kv0 + 63 > CLn + wrow0){
      const int lim = CLn + myq;
      #pragma unroll
      for (int r=0;r<16;++r){
        const int kl = (r&3) + 8*(r>>2) + 4*h;
        if (kv0 + kl      > lim) sc0[r] = -1e30f;
        if (kv0 + 32 + kl > lim) sc1[r] = -1e30f;
      }
    }
    // row max: 31 in-lane fmax + cross-half
    float mt = sc0[0];
    #pragma unroll
    for (int r=1;r<16;++r) mt = fmaxf(mt, sc0[r]);
    #pragma unroll
    for (int r=0;r<16;++r) mt = fmaxf(mt, sc1[r]);
    mt = fmaxf(mt, __shfl_xor(mt, 32));
    mt = fmaxf(mt, -1e20f);
    if (!__all(mt - m_st <= 11.54f)){   // defer-max (8 nats, log2 domain)
      const float mn = fmaxf(m_st, mt);
      const float corr = exp2f(m_st - mn);
      m_st = mn;
      l_st *= corr;
      #pragma unroll
      for (int r=0;r<16;++r){
        const int qrow = (r&3) + 8*(r>>2) + 4*h;
        const float ca = __shfl(corr, qrow);
        #pragma unroll
        for (int db=0;db<4;++db) acc[db][r] *= ca;
      }
    }
    // P = exp2(sc - m), row sum (in-lane + cross-half)
    float rs = 0.f;
    #pragma unroll
    for (int r=0;r<16;++r){
      const float p0 = exp2f(sc0[r] - m_st);
      const float p1 = exp2f(sc1[r] - m_st);
      sc0[r] = p0; sc1[r] = p1;
      rs += p0 + p1;
    }
    rs += __shfl_xor(rs, 32);
    l_st += rs;
    // P -> wave-private LDS in D-layout (adjacent-k pairs pack to u32)
    #pragma unroll
    for (int r=0;r<16;r+=2){
      const int kl = (r&3) + 8*(r>>2) + 4*h;      // even r -> even kl
      *(unsigned*)(Pw + l31*128 + ((kl*2)        ^ xswp)) = pk2(sc0[r], sc0[r+1]);
      *(unsigned*)(Pw + l31*128 + (((kl+32)*2)   ^ xswp)) = pk2(sc1[r], sc1[r+1]);
    }
    // PV: A-frag read back (P[q=l31][k = s*16 + h*8 + e]), B = V^T frag
    #pragma unroll
    for (int s=0;s<4;++s){
      bfx8 pa = *(const bfx8*)(Pw + l31*128 + ((s*32 + h*16) ^ xswp));
      const int vb = s*32 + h*16;
      #pragma unroll
      for (int db=0;db<4;++db){
        const int vrow = db*32 + l31;
        bfx8 vf = *(const bfx8*)(Vc + vrow*128 + (vb ^ ((vrow & 7) << 4)));
        acc[db] = MFMA32(pa, vf, acc[db]);
      }
    }
    cur ^= 1;
  }
  // epilogue: acc row q = wrow0 + (reg&3)+8*(reg>>2)+4h, col d = db*32 + l31
  if (nsplit == 1){
    const float linv = 1.0f / l_st;
    #pragma unroll
    for (int r=0;r<16;++r){
      const int qrow = (r&3) + 8*(r>>2) + 4*h;
      const float inv = __shfl(linv, qrow);
      const int qr = wrow0 + qrow;
      if (qr < S_){
        #pragma unroll
        for (int db=0;db<4;++db)
          O[(size_t)qr*DIMN + hh*HDIM + db*32 + l31] = f2bf(acc[db][r]*inv);
      }
    }
  } else {
    #pragma unroll
    for (int r=0;r<16;++r){
      const int qrow = (r&3) + 8*(r>>2) + 4*h;
      const int qr = wrow0 + qrow;
      if (qr < S_){
        const size_t rid = ((size_t)z*NH + hh)*S_ + qr;
        float* dst = pacc + rid*128;
        #pragma unroll
        for (int db=0;db<4;++db) dst[db*32 + l31] = acc[db][r];
      }
    }
    if (lane < 32 && myq < S_){
      const size_t rid2 = ((size_t)z*NH + hh)*S_ + myq;
      pml[rid2*2]   = m_st;
      pml[rid2*2+1] = l_st;
    }
  }
}

// ---------------- combine partials -> ob bf16 (exp2 domain m) ----------------
__global__ __launch_bounds__(256) void combine_kernel(const float* __restrict__ pacc,
    const float* __restrict__ pml, unsigned short* __restrict__ ob, int S_, int nsplit){
  const int t = threadIdx.x;
  const int rid = blockIdx.x*2 + (t >> 7);   // hh*S_+q
  if (rid >= S_*NH) return;
  const int d = t & 127;
  const int hh = rid / S_;
  const int q  = rid - hh*S_;
  float M = -1e20f;
  for (int s=0; s<nsplit; ++s)
    M = fmaxf(M, pml[((size_t)s*NH*S_ + rid)*2]);
  float lt = 0.f, o = 0.f;
  for (int s=0; s<nsplit; ++s){
    const float m = pml[((size_t)s*NH*S_ + rid)*2];
    const float l = pml[((size_t)s*NH*S_ + rid)*2 + 1];
    const float wgt = exp2f(m - M);
    lt += l * wgt;
    o  += pacc[((size_t)s*NH*S_ + rid)*128 + d] * wgt;
  }
  if (lt == 0.f) lt = 1.f;
  ob[(size_t)q*DIMN + hh*HDIM + d] = f2bf(o / lt);
}

extern "C" void kernel_launch(void* const* d_in, const int* in_sizes, int n_in,
                              void* d_out, int out_size, void* d_ws, size_t ws_size,
                              hipStream_t stream){
  const float* x       = (const float*)d_in[0];
  const float* freqs   = (const float*)d_in[1];
  const float* k_cache = (const float*)d_in[2];
  const float* v_cache = (const float*)d_in[3];
  const float* Wq = (const float*)d_in[4];
  const float* bq = (const float*)d_in[5];
  const float* Wk = (const float*)d_in[6];
  const float* bk = (const float*)d_in[7];
  const float* Wv = (const float*)d_in[8];
  const float* bv = (const float*)d_in[9];
  const float* Wo = (const float*)d_in[10];
  const float* bo = (const float*)d_in[11];
  const float* gq = (const float*)d_in[12];
  const float* gk = (const float*)d_in[13];
  const int*   cur = (const int*)d_in[14];

  const int S = in_sizes[0] / DIMN;
  const int CACHE_ = in_sizes[2] / DIMN;
  const int L = CACHE_ + S;
  const int CLn = L - S;

  auto al = [](size_t n){ return (n + 255) & ~(size_t)255; };
  char* base = (char*)d_ws;
  size_t off = 0;
  auto take = [&](size_t n){ char* r = base + off; off += al(n); return r; };
  // persistent:
  unsigned short* xb  = (unsigned short*)take((size_t)S*DIMN*2);
  unsigned short* Wob = (unsigned short*)take((size_t)DIMN*DIMN*2);
  unsigned short* qb  = (unsigned short*)take((size_t)NH*S*HDIM*2);
  unsigned short* kb  = (unsigned short*)take((size_t)NH*L*HDIM*2);
  unsigned short* vtb = (unsigned short*)take((size_t)NH*HDIM*L*2);
  unsigned short* ob  = (unsigned short*)take((size_t)S*DIMN*2);
  const size_t ubase = off;
  // union pool A: transients (dead before attn): lin0/1/2 (bf16) + Wq/Wk/Wv (bf16)
  const size_t l_sz = al((size_t)S*DIMN*2);
  const size_t w_sz = al((size_t)DIMN*DIMN*2);
  unsigned short* lin0 = (unsigned short*)(base + ubase);
  unsigned short* lin1 = (unsigned short*)(base + ubase + l_sz);
  unsigned short* lin2 = (unsigned short*)(base + ubase + 2*l_sz);
  unsigned short* Wqb  = (unsigned short*)(base + ubase + 3*l_sz);
  unsigned short* Wkb  = (unsigned short*)(base + ubase + 3*l_sz + w_sz);
  unsigned short* Wvb  = (unsigned short*)(base + ubase + 3*l_sz + 2*w_sz);
  const size_t trans_sz = 3*l_sz + 3*w_sz;
  // union pool B: attention partials
  auto pool_sz = [&](int ns){
    return al((size_t)ns*NH*S*HDIM*4) + al((size_t)ns*NH*S*2*4);
  };
  int nsplit = 1;
  if (ubase + (trans_sz > pool_sz(4) ? trans_sz : pool_sz(4)) <= ws_size) nsplit = 4;
  else if (ubase + (trans_sz > pool_sz(2) ? trans_sz : pool_sz(2)) <= ws_size) nsplit = 2;
  if (ubase + trans_sz > ws_size) return;
  float* pacc = (float*)(base + ubase);
  float* pml  = (float*)(base + ubase + al((size_t)nsplit*NH*S*HDIM*4));

  const int wn8 = DIMN*DIMN/8;
  cast_bf16_kernel<<<(S*DIMN/8+255)/256, 256, 0, stream>>>(x,  xb,  S*DIMN/8);
  cast_bf16_kernel<<<(wn8+255)/256, 256, 0, stream>>>(Wq, Wqb, wn8);
  cast_bf16_kernel<<<(wn8+255)/256, 256, 0, stream>>>(Wk, Wkb, wn8);
  cast_bf16_kernel<<<(wn8+255)/256, 256, 0, stream>>>(Wv, Wvb, wn8);
  cast_bf16_kernel<<<(wn8+255)/256, 256, 0, stream>>>(Wo, Wob, wn8);
  kcache_kernel<<<CACHE_, 256, 0, stream>>>(k_cache, kb, CACHE_, L);
  vtrans_kernel<<<dim3((CACHE_+63)/64, 4, NH), 256, 0, stream>>>(v_cache, vtb, CACHE_, 0, L);

  const int mb = (S+127)/128;
  gemm_qkv<<<dim3(DIMN/128, mb, 3), 256, 0, stream>>>(xb, Wqb, Wkb, Wvb, bq, bk, bv,
                                                      lin0, lin1, lin2, S, DIMN, DIMN);
  const float qsc = 0.08838834764831845f * 1.4426950408889634f;
  norm_rope_kernel<<<S, 256, 0, stream>>>(lin0, gq, freqs, cur, qb, S, (size_t)S*HDIM, 0, qsc);
  norm_rope_kernel<<<S, 256, 0, stream>>>(lin1, gk, freqs, cur, kb, S, (size_t)L*HDIM, CACHE_, 1.0f);
  vtrans_bf16_kernel<<<dim3((S+63)/64, 4, NH), 256, 0, stream>>>(lin2, vtb, S, CACHE_, L);

  const int nx = (S+127)/128;
  attn_kernel<<<nx*NH*nsplit, 256, 0, stream>>>(qb, kb, vtb, ob,
                                                pacc, pml, S, L, CLn, nx, nsplit);
  if (nsplit > 1)
    combine_kernel<<<(S*NH+1)/2, 256, 0, stream>>>(pacc, pml, ob, S, nsplit);
  gemm_bt<<<dim3(DIMN/128, mb), 256, 0, stream>>>(ob, Wob, bo, (float*)d_out, S, DIMN, DIMN);
}

// Round 12
// 504.685 us; speedup vs baseline: 1.3063x; 1.0240x over previous
//
#include <hip/hip_runtime.h>

#define DIMN 2048
#define NH 16
#define HDIM 128

typedef __attribute__((ext_vector_type(4))) float f32x4;
typedef __attribute__((ext_vector_type(16))) float f32x16;
typedef __attribute__((ext_vector_type(8))) __bf16 bfx8;
typedef __attribute__((ext_vector_type(4))) __bf16 bf16x4;
typedef __attribute__((ext_vector_type(2))) __bf16 bf16x2;
typedef __attribute__((ext_vector_type(8))) unsigned short u16x8;

__device__ __forceinline__ unsigned short f2bf(float f){
  unsigned u = __builtin_bit_cast(unsigned, f);
  u += 0x7fffu + ((u >> 16) & 1u);
  return (unsigned short)(u >> 16);
}
__device__ __forceinline__ float bf2f(unsigned short h){
  unsigned u = (unsigned)h << 16;
  return __builtin_bit_cast(float, u);
}

__device__ __forceinline__ void gl_lds16(const void* g, void* l){
  __builtin_amdgcn_global_load_lds((const __attribute__((address_space(1))) void*)g,
                                   (__attribute__((address_space(3))) void*)l, 16, 0, 0);
}

// m204 bijective XCD-chunked remap (works for any nwg)
__device__ __forceinline__ int xcd_swz(int bid, int nwg){
  const int q = nwg >> 3, r = nwg & 7;
  const int xcd = bid & 7, idx = bid >> 3;
  return (xcd < r ? xcd*(q+1) : r*(q+1) + (xcd-r)*q) + idx;
}

#define MFMA16(a,b,c) __builtin_amdgcn_mfma_f32_16x16x32_bf16((a),(b),(c),0,0,0)
#define MFMA32(a,b,c) __builtin_amdgcn_mfma_f32_32x32x16_bf16((a),(b),(c),0,0,0)

// ---------------- elementwise f32 -> bf16 cast ----------------
__global__ __launch_bounds__(256) void cast_bf16_kernel(const float* __restrict__ in,
                                                        unsigned short* __restrict__ out, int n8){
  int i = blockIdx.x*256 + threadIdx.x;
  if (i >= n8) return;
  const float4* p = (const float4*)(in + (size_t)i*8);
  float4 a = p[0], b = p[1];
  u16x8 o;
  o[0]=f2bf(a.x); o[1]=f2bf(a.y); o[2]=f2bf(a.z); o[3]=f2bf(a.w);
  o[4]=f2bf(b.x); o[5]=f2bf(b.y); o[6]=f2bf(b.z); o[7]=f2bf(b.w);
  *(u16x8*)(out + (size_t)i*8) = o;
}

// ---------------- k_cache (CACHE,H,HD) f32 -> kb[h][k][d] bf16 ----------------
__global__ __launch_bounds__(256) void kcache_kernel(const float* __restrict__ kc,
                                                     unsigned short* __restrict__ kb,
                                                     int R, int L_){
  const int gid = blockIdx.x*256 + threadIdx.x;
  if (gid >= R*256) return;
  const size_t idx = (size_t)gid * 8;
  const int k   = (int)(idx >> 11);
  const int rem = (int)(idx & 2047);
  const int hh  = rem >> 7, d = rem & 127;
  const float4* p = (const float4*)(kc + idx);
  float4 a = p[0], b = p[1];
  u16x8 o;
  o[0]=f2bf(a.x); o[1]=f2bf(a.y); o[2]=f2bf(a.z); o[3]=f2bf(a.w);
  o[4]=f2bf(b.x); o[5]=f2bf(b.y); o[6]=f2bf(b.z); o[7]=f2bf(b.w);
  *(u16x8*)(kb + (size_t)hh*L_*HDIM + (size_t)k*HDIM + d) = o;
}

// ---------------- (R,H,HD) f32 -> vt[h][d][koff+k] bf16 (transpose) ----------------
__global__ __launch_bounds__(256) void vtrans_kernel(const float* __restrict__ src,
                                                     unsigned short* __restrict__ vt,
                                                     int R, int koff, int L_){
  __shared__ __align__(16) unsigned short tile[32][72];
  const int kb0 = blockIdx.x * 64, db0 = blockIdx.y * 32, hh = blockIdx.z;
  const int t = threadIdx.x;
  const int kk = t >> 2, dd = (t & 3) * 8;
  const int k = kb0 + kk;
  if (k < R){
    const float* p = src + (size_t)k*DIMN + hh*HDIM + db0 + dd;
    float4 a = ((const float4*)p)[0], b = ((const float4*)p)[1];
    tile[dd+0][kk] = f2bf(a.x); tile[dd+1][kk] = f2bf(a.y);
    tile[dd+2][kk] = f2bf(a.z); tile[dd+3][kk] = f2bf(a.w);
    tile[dd+4][kk] = f2bf(b.x); tile[dd+5][kk] = f2bf(b.y);
    tile[dd+6][kk] = f2bf(b.z); tile[dd+7][kk] = f2bf(b.w);
  }
  __syncthreads();
  const int d = t >> 3, k0 = (t & 7) * 8;
  unsigned short* dst = vt + (size_t)hh*HDIM*L_ + (size_t)(db0+d)*L_ + koff + kb0 + k0;
  if (kb0 + k0 + 8 <= R){
    *(u16x8*)dst = *(const u16x8*)&tile[d][k0];
  } else {
    #pragma unroll
    for (int e=0;e<8;++e) if (kb0 + k0 + e < R) dst[e] = tile[d][k0+e];
  }
}

// ---------------- same but bf16 source (projected V) ----------------
__global__ __launch_bounds__(256) void vtrans_bf16_kernel(const unsigned short* __restrict__ src,
    unsigned short* __restrict__ vt, int R, int koff, int L_){
  __shared__ __align__(16) unsigned short tile[32][72];
  const int kb0 = blockIdx.x * 64, db0 = blockIdx.y * 32, hh = blockIdx.z;
  const int t = threadIdx.x;
  const int kk = t >> 2, dd = (t & 3) * 8;
  const int k = kb0 + kk;
  if (k < R){
    u16x8 a = *(const u16x8*)(src + (size_t)k*DIMN + hh*HDIM + db0 + dd);
    #pragma unroll
    for (int e=0;e<8;++e) tile[dd+e][kk] = a[e];
  }
  __syncthreads();
  const int d = t >> 3, k0 = (t & 7) * 8;
  unsigned short* dst = vt + (size_t)hh*HDIM*L_ + (size_t)(db0+d)*L_ + koff + kb0 + k0;
  if (kb0 + k0 + 8 <= R){
    *(u16x8*)dst = *(const u16x8*)&tile[d][k0];
  } else {
    #pragma unroll
    for (int e=0;e<8;++e) if (kb0 + k0 + e < R) dst[e] = tile[d][k0+e];
  }
}

// ---------------- fused rmsnorm + interleaved RoPE (bf16 in), bf16 head-major out ----
__global__ __launch_bounds__(256) void norm_rope_kernel(const unsigned short* __restrict__ lin,
    const float* __restrict__ g, const float* __restrict__ freqs, const int* __restrict__ cur,
    unsigned short* __restrict__ out, int S_, size_t head_stride, int row_off, float oscale){
  const int q = blockIdx.x, t = threadIdx.x;
  u16x8 v = *(const u16x8*)(lin + (size_t)q*DIMN + t*8);
  float x[8];
  #pragma unroll
  for (int e=0;e<8;++e) x[e] = bf2f(v[e]);
  float ss = 0.f;
  #pragma unroll
  for (int e=0;e<8;++e) ss += x[e]*x[e];
  for (int m=1;m<64;m<<=1) ss += __shfl_xor(ss, m);
  __shared__ float red[4];
  if ((t & 63) == 0) red[t>>6] = ss;
  __syncthreads();
  const float tot = red[0]+red[1]+red[2]+red[3];
  const float rstd = rsqrtf(tot * (1.0f/2048.0f) + 1e-6f);
  const int n0 = t*8;
  float xr[8];
  #pragma unroll
  for (int e=0;e<8;++e) xr[e] = x[e] * rstd * g[n0+e];
  const int pos = cur[0] + q;
  const int hh = n0 >> 7, d0 = n0 & 127;
  const float* fr = freqs + (size_t)pos * HDIM;
  float o[8];
  #pragma unroll
  for (int p=0;p<4;++p){
    const int j = (d0>>1) + p;
    const float c = fr[j], s = fr[64+j];
    o[2*p]   = xr[2*p]*c - xr[2*p+1]*s;
    o[2*p+1] = xr[2*p+1]*c + xr[2*p]*s;
  }
  u16x8 ov;
  #pragma unroll
  for (int e=0;e<8;++e) ov[e] = f2bf(o[e]*oscale);
  *(u16x8*)(out + (size_t)hh*head_stride + (size_t)(q+row_off)*HDIM + d0) = ov;
}

// ---------------- C[M,N] = A[M,K] * B[N,K]^T + bias, bf16 in fp32 out ----------------
// 1D grid with XCD-chunked swizzle (T1); decode by-fastest (B-panel L2 locality).
__global__ __launch_bounds__(256,2) void gemm_bt(const unsigned short* __restrict__ A,
    const unsigned short* __restrict__ B, const float* __restrict__ bias,
    float* __restrict__ C, int M, int N, int K){
  __shared__ __align__(16) unsigned short As[128*64];
  __shared__ __align__(16) unsigned short Bs[128*64];
  const int mb = (M + 127) >> 7;
  const int swz = xcd_swz(blockIdx.x, gridDim.x);
  const int bx = swz / mb, by = swz % mb;
  const int t = threadIdx.x;
  const int w = t >> 6, lane = t & 63, lh = lane >> 4, ll = lane & 15;
  const int wr = w >> 1, wc = w & 1;
  const int m0 = by * 128, n0 = bx * 128;
  const int srow = t >> 3;
  const int scb  = (t & 7) * 16;
  const int swc  = (scb ^ ((srow & 7) << 4)) >> 1;
  int arow[4]; size_t brow[4];
  #pragma unroll
  for (int c=0;c<4;++c){
    int r = m0 + c*32 + srow; if (r >= M) r = M-1;
    arow[c] = r;
    brow[c] = (size_t)(n0 + c*32 + srow);
  }
  const int xsw = (ll & 7) << 4;
  f32x4 acc[4][4] = {};
  const int nk = K >> 6;
  for (int kt = 0; kt < nk; ++kt){
    const int k0 = kt << 6;
    #pragma unroll
    for (int c=0;c<4;++c){
      gl_lds16(A + (size_t)arow[c]*K + k0 + swc, (char*)As + c*4096 + w*1024);
      gl_lds16(B + brow[c]*K       + k0 + swc, (char*)Bs + c*4096 + w*1024);
    }
    asm volatile("s_waitcnt vmcnt(0)" ::: "memory");
    __syncthreads();
    #pragma unroll
    for (int kk=0;kk<2;++kk){
      const int cb = kk*64 + lh*16;
      bfx8 a[4], b[4];
      #pragma unroll
      for (int i=0;i<4;++i)
        a[i] = *(const bfx8*)((const char*)As + (wr*64 + i*16 + ll)*128 + (cb ^ xsw));
      #pragma unroll
      for (int j=0;j<4;++j)
        b[j] = *(const bfx8*)((const char*)Bs + (wc*64 + j*16 + ll)*128 + (cb ^ xsw));
      #pragma unroll
      for (int i=0;i<4;++i)
        #pragma unroll
        for (int j=0;j<4;++j)
          acc[i][j] = MFMA16(a[i], b[j], acc[i][j]);
    }
    __syncthreads();
  }
  #pragma unroll
  for (int i=0;i<4;++i){
    #pragma unroll
    for (int j=0;j<4;++j){
      const int col = n0 + wc*64 + j*16 + ll;
      const float bb = bias[col];
      #pragma unroll
      for (int r=0;r<4;++r){
        const int row = m0 + wr*64 + i*16 + lh*4 + r;
        if (row < M) C[(size_t)row*N + col] = acc[i][j][r] + bb;
      }
    }
  }
}

// ---------------- fused QKV gemm (1D grid + XCD swizzle); bf16 out ----------------
__global__ __launch_bounds__(256,2) void gemm_qkv(const unsigned short* __restrict__ A,
    const unsigned short* __restrict__ B0, const unsigned short* __restrict__ B1,
    const unsigned short* __restrict__ B2, const float* __restrict__ g0,
    const float* __restrict__ g1, const float* __restrict__ g2,
    unsigned short* __restrict__ C0, unsigned short* __restrict__ C1,
    unsigned short* __restrict__ C2, int M, int N, int K){
  const int mb = (M + 127) >> 7;
  const int nxt = N >> 7;
  const int per = nxt * mb;
  const int swz = xcd_swz(blockIdx.x, gridDim.x);
  const int zz = swz / per;
  const int rem = swz - zz * per;
  const int bx = rem / mb, by = rem % mb;
  const unsigned short* B = (zz==0) ? B0 : (zz==1) ? B1 : B2;
  const float* bias       = (zz==0) ? g0 : (zz==1) ? g1 : g2;
  unsigned short* C       = (zz==0) ? C0 : (zz==1) ? C1 : C2;
  __shared__ __align__(16) unsigned short As[128*64];
  __shared__ __align__(16) unsigned short Bs[128*64];
  const int t = threadIdx.x;
  const int w = t >> 6, lane = t & 63, lh = lane >> 4, ll = lane & 15;
  const int wr = w >> 1, wc = w & 1;
  const int m0 = by * 128, n0 = bx * 128;
  const int srow = t >> 3;
  const int scb  = (t & 7) * 16;
  const int swc  = (scb ^ ((srow & 7) << 4)) >> 1;
  int arow[4]; size_t brow[4];
  #pragma unroll
  for (int c=0;c<4;++c){
    int r = m0 + c*32 + srow; if (r >= M) r = M-1;
    arow[c] = r;
    brow[c] = (size_t)(n0 + c*32 + srow);
  }
  const int xsw = (ll & 7) << 4;
  f32x4 acc[4][4] = {};
  const int nk = K >> 6;
  for (int kt = 0; kt < nk; ++kt){
    const int k0 = kt << 6;
    #pragma unroll
    for (int c=0;c<4;++c){
      gl_lds16(A + (size_t)arow[c]*K + k0 + swc, (char*)As + c*4096 + w*1024);
      gl_lds16(B + brow[c]*K       + k0 + swc, (char*)Bs + c*4096 + w*1024);
    }
    asm volatile("s_waitcnt vmcnt(0)" ::: "memory");
    __syncthreads();
    #pragma unroll
    for (int kk=0;kk<2;++kk){
      const int cb = kk*64 + lh*16;
      bfx8 a[4], b[4];
      #pragma unroll
      for (int i=0;i<4;++i)
        a[i] = *(const bfx8*)((const char*)As + (wr*64 + i*16 + ll)*128 + (cb ^ xsw));
      #pragma unroll
      for (int j=0;j<4;++j)
        b[j] = *(const bfx8*)((const char*)Bs + (wc*64 + j*16 + ll)*128 + (cb ^ xsw));
      #pragma unroll
      for (int i=0;i<4;++i)
        #pragma unroll
        for (int j=0;j<4;++j)
          acc[i][j] = MFMA16(a[i], b[j], acc[i][j]);
    }
    __syncthreads();
  }
  #pragma unroll
  for (int i=0;i<4;++i){
    #pragma unroll
    for (int j=0;j<4;++j){
      const int col = n0 + wc*64 + j*16 + ll;
      const float bb = bias[col];
      #pragma unroll
      for (int r=0;r<4;++r){
        const int row = m0 + wr*64 + i*16 + lh*4 + r;
        if (row < M) C[(size_t)row*N + col] = f2bf(acc[i][j][r] + bb);
      }
    }
  }
}

// ---------------- flash attention: 4 waves, 32x32x16 MFMA, P via LDS ----------------
// R11 structure (verified) + T5 setprio around MFMA clusters + b64 P-store
// (4 adjacent k per write: regs r=4i+j map to k=8i+4h+j).
__global__ __launch_bounds__(256,2) void attn_kernel(const unsigned short* __restrict__ Q,
    const unsigned short* __restrict__ K, const unsigned short* __restrict__ VT,
    unsigned short* __restrict__ O, float* __restrict__ pacc, float* __restrict__ pml,
    int S_, int L_, int CLn, int nx, int nsplit){
  __shared__ __align__(16) unsigned short Ks[2][64*128];
  __shared__ __align__(16) unsigned short Vs[2][128*64];
  __shared__ __align__(16) unsigned short Ps[4][32*64];
  const int nwg = gridDim.x;
  const int swzid = (blockIdx.x & 7)*(nwg >> 3) + (blockIdx.x >> 3);
  const int xq = swzid % nx;
  const int rest = swzid / nx;
  const int hh = rest % NH;
  const int z  = rest / NH;
  const int q0 = xq * 128;
  const int t = threadIdx.x, w = t >> 6, lane = t & 63;
  const int l31 = lane & 31, h = lane >> 5;
  char* Pw = (char*)Ps[w];
  const int xswp = (l31 & 7) << 4;
  const unsigned short* Qh = Q  + (size_t)hh*S_*HDIM;
  const unsigned short* Kh = K  + (size_t)hh*L_*HDIM;
  const unsigned short* Vh = VT + (size_t)hh*HDIM*L_;
  const int wrow0 = q0 + w*32;
  const int myq = wrow0 + l31;            // this lane's q-row (state + QK^T col)
  // Q fragment (B-operand of 32x32x16): lane holds Q[myq][kk*16 + h*8 .. +7]
  bfx8 qf[8];
  {
    int qr = myq; if (qr >= S_) qr = S_ - 1;
    #pragma unroll
    for (int kk=0;kk<8;++kk)
      qf[kk] = *(const bfx8*)(Qh + (size_t)qr*HDIM + kk*16 + h*8);
  }
  f32x16 acc[4] = {};                     // [db]: O[q(reg,h)][db*32 + l31]
  float m_st = -1e20f, l_st = 0.f;
  int qlast = q0 + 127; if (qlast >= S_) qlast = S_ - 1;
  const int kend = CLn + qlast + 1;
  const int nt = (kend + 63) >> 6;
  const int tps = (nt + nsplit - 1) / nsplit;
  const int t0 = z * tps;
  int t1 = t0 + tps; if (t1 > nt) t1 = nt;
  const int ksrow = t >> 4, kchunk = t & 15;
  const int vsrow = t >> 3, vchunk = t & 7;
  const int last = nt - 1;

  u16x8 kreg[4], vreg[4];
  auto load_tile = [&](int ktile){
    const int kv0 = ktile << 6;
    if (ktile == last){
      #pragma unroll
      for (int c=0;c<4;++c){
        int krow = kv0 + c*16 + ksrow; if (krow >= L_) krow = L_ - 1;
        kreg[c] = *(const u16x8*)(Kh + (size_t)krow*HDIM + kchunk*8);
      }
      int vcol = kv0 + vchunk*8; if (vcol > L_ - 8) vcol = L_ - 8;
      #pragma unroll
      for (int c=0;c<4;++c)
        vreg[c] = *(const u16x8*)(Vh + (size_t)(c*32 + vsrow)*L_ + vcol);
    } else {
      #pragma unroll
      for (int c=0;c<4;++c)
        kreg[c] = *(const u16x8*)(Kh + (size_t)(kv0 + c*16 + ksrow)*HDIM + kchunk*8);
      const int vcol = kv0 + vchunk*8;
      #pragma unroll
      for (int c=0;c<4;++c)
        vreg[c] = *(const u16x8*)(Vh + (size_t)(c*32 + vsrow)*L_ + vcol);
    }
  };
  auto stage_write = [&](int b){
    #pragma unroll
    for (int c=0;c<4;++c)
      *(u16x8*)((char*)Ks[b] + (c*16 + ksrow)*256 + ((kchunk*16) ^ ((ksrow & 7) << 4))) = kreg[c];
    #pragma unroll
    for (int c=0;c<4;++c)
      *(u16x8*)((char*)Vs[b] + (c*32 + vsrow)*128 + ((vchunk*16) ^ ((vsrow & 7) << 4))) = vreg[c];
  };

  if (t0 < t1){
    load_tile(t0);
    stage_write(0);
    if (t0 + 1 < t1) load_tile(t0 + 1);
  }
  const int krow0 = l31,      koff0 = (krow0 & 7) << 4;   // j=0 K rows
  const int krow1 = 32 + l31, koff1 = (krow1 & 7) << 4;   // j=1 K rows
  int cur = 0;
  for (int kt = t0; kt < t1; ++kt){
    const int kv0 = kt << 6;
    __syncthreads();   // buf[cur] visible; all waves done with buf[cur^1]
    const char* Kc = (const char*)Ks[cur];
    const char* Vc = (const char*)Vs[cur];
    // QK^T: sc_j[reg] = S[k = kv0 + 32j + (reg&3)+8*(reg>>2)+4h][q = myq]
    f32x16 sc0 = {}, sc1 = {};
    __builtin_amdgcn_s_setprio(1);
    #pragma unroll
    for (int kk=0;kk<8;++kk){
      const int cb = kk*32 + h*16;
      bfx8 kf0 = *(const bfx8*)(Kc + krow0*256 + (cb ^ koff0));
      bfx8 kf1 = *(const bfx8*)(Kc + krow1*256 + (cb ^ koff1));
      sc0 = MFMA32(kf0, qf[kk], sc0);
      sc1 = MFMA32(kf1, qf[kk], sc1);
    }
    __builtin_amdgcn_s_setprio(0);
    if (kt + 1 < t1){
      stage_write(cur ^ 1);
      if (kt + 2 < t1) load_tile(kt + 2);
    }
    // causal mask (scale*log2e folded into Q)
    if (kv0 + 63 > CLn + wrow0){
      const int lim = CLn + myq;
      #pragma unroll
      for (int r=0;r<16;++r){
        const int kl = (r&3) + 8*(r>>2) + 4*h;
        if (kv0 + kl      > lim) sc0[r] = -1e30f;
        if (kv0 + 32 + kl > lim) sc1[r] = -1e30f;
      }
    }
    // row max: 31 in-lane fmax + cross-half
    float mt = sc0[0];
    #pragma unroll
    for (int r=1;r<16;++r) mt = fmaxf(mt, sc0[r]);
    #pragma unroll
    for (int r=0;r<16;++r) mt = fmaxf(mt, sc1[r]);
    mt = fmaxf(mt, __shfl_xor(mt, 32));
    mt = fmaxf(mt, -1e20f);
    if (!__all(mt - m_st <= 11.54f)){   // defer-max (8 nats, log2 domain)
      const float mn = fmaxf(m_st, mt);
      const float corr = exp2f(m_st - mn);
      m_st = mn;
      l_st *= corr;
      #pragma unroll
      for (int r=0;r<16;++r){
        const int qrow = (r&3) + 8*(r>>2) + 4*h;
        const float ca = __shfl(corr, qrow);
        #pragma unroll
        for (int db=0;db<4;++db) acc[db][r] *= ca;
      }
    }
    // P = exp2(sc - m), row sum (in-lane + cross-half)
    float rs = 0.f;
    #pragma unroll
    for (int r=0;r<16;++r){
      const float p0 = exp2f(sc0[r] - m_st);
      const float p1 = exp2f(sc1[r] - m_st);
      sc0[r] = p0; sc1[r] = p1;
      rs += p0 + p1;
    }
    rs += __shfl_xor(rs, 32);
    l_st += rs;
    // P -> wave-private LDS, b64 writes: regs r=4i+j -> k = 8i+4h+j (adjacent j)
    #pragma unroll
    for (int i=0;i<4;++i){
      bf16x4 p0 = { (__bf16)sc0[4*i], (__bf16)sc0[4*i+1], (__bf16)sc0[4*i+2], (__bf16)sc0[4*i+3] };
      bf16x4 p1 = { (__bf16)sc1[4*i], (__bf16)sc1[4*i+1], (__bf16)sc1[4*i+2], (__bf16)sc1[4*i+3] };
      const int kb0b = (8*i + 4*h) * 2;          // byte offset of k within P row
      *(bf16x4*)(Pw + l31*128 + (kb0b        ^ xswp)) = p0;
      *(bf16x4*)(Pw + l31*128 + ((64 + kb0b) ^ xswp)) = p1;
    }
    // PV: A-frag read back (P[q=l31][k = s*16 + h*8 + e]), B = V^T frag
    __builtin_amdgcn_s_setprio(1);
    #pragma unroll
    for (int s=0;s<4;++s){
      bfx8 pa = *(const bfx8*)(Pw + l31*128 + ((s*32 + h*16) ^ xswp));
      const int vb = s*32 + h*16;
      #pragma unroll
      for (int db=0;db<4;++db){
        const int vrow = db*32 + l31;
        bfx8 vf = *(const bfx8*)(Vc + vrow*128 + (vb ^ ((vrow & 7) << 4)));
        acc[db] = MFMA32(pa, vf, acc[db]);
      }
    }
    __builtin_amdgcn_s_setprio(0);
    cur ^= 1;
  }
  // epilogue: acc row q = wrow0 + (reg&3)+8*(reg>>2)+4h, col d = db*32 + l31
  if (nsplit == 1){
    const float linv = 1.0f / l_st;
    #pragma unroll
    for (int r=0;r<16;++r){
      const int qrow = (r&3) + 8*(r>>2) + 4*h;
      const float inv = __shfl(linv, qrow);
      const int qr = wrow0 + qrow;
      if (qr < S_){
        #pragma unroll
        for (int db=0;db<4;++db)
          O[(size_t)qr*DIMN + hh*HDIM + db*32 + l31] = f2bf(acc[db][r]*inv);
      }
    }
  } else {
    #pragma unroll
    for (int r=0;r<16;++r){
      const int qrow = (r&3) + 8*(r>>2) + 4*h;
      const int qr = wrow0 + qrow;
      if (qr < S_){
        const size_t rid = ((size_t)z*NH + hh)*S_ + qr;
        float* dst = pacc + rid*128;
        #pragma unroll
        for (int db=0;db<4;++db) dst[db*32 + l31] = acc[db][r];
      }
    }
    if (lane < 32 && myq < S_){
      const size_t rid2 = ((size_t)z*NH + hh)*S_ + myq;
      pml[rid2*2]   = m_st;
      pml[rid2*2+1] = l_st;
    }
  }
}

// ---------------- combine partials -> ob bf16 (exp2 domain m) ----------------
__global__ __launch_bounds__(256) void combine_kernel(const float* __restrict__ pacc,
    const float* __restrict__ pml, unsigned short* __restrict__ ob, int S_, int nsplit){
  const int t = threadIdx.x;
  const int rid = blockIdx.x*2 + (t >> 7);   // hh*S_+q
  if (rid >= S_*NH) return;
  const int d = t & 127;
  const int hh = rid / S_;
  const int q  = rid - hh*S_;
  float M = -1e20f;
  for (int s=0; s<nsplit; ++s)
    M = fmaxf(M, pml[((size_t)s*NH*S_ + rid)*2]);
  float lt = 0.f, o = 0.f;
  for (int s=0; s<nsplit; ++s){
    const float m = pml[((size_t)s*NH*S_ + rid)*2];
    const float l = pml[((size_t)s*NH*S_ + rid)*2 + 1];
    const float wgt = exp2f(m - M);
    lt += l * wgt;
    o  += pacc[((size_t)s*NH*S_ + rid)*128 + d] * wgt;
  }
  if (lt == 0.f) lt = 1.f;
  ob[(size_t)q*DIMN + hh*HDIM + d] = f2bf(o / lt);
}

extern "C" void kernel_launch(void* const* d_in, const int* in_sizes, int n_in,
                              void* d_out, int out_size, void* d_ws, size_t ws_size,
                              hipStream_t stream){
  const float* x       = (const float*)d_in[0];
  const float* freqs   = (const float*)d_in[1];
  const float* k_cache = (const float*)d_in[2];
  const float* v_cache = (const float*)d_in[3];
  const float* Wq = (const float*)d_in[4];
  const float* bq = (const float*)d_in[5];
  const float* Wk = (const float*)d_in[6];
  const float* bk = (const float*)d_in[7];
  const float* Wv = (const float*)d_in[8];
  const float* bv = (const float*)d_in[9];
  const float* Wo = (const float*)d_in[10];
  const float* bo = (const float*)d_in[11];
  const float* gq = (const float*)d_in[12];
  const float* gk = (const float*)d_in[13];
  const int*   cur = (const int*)d_in[14];

  const int S = in_sizes[0] / DIMN;
  const int CACHE_ = in_sizes[2] / DIMN;
  const int L = CACHE_ + S;
  const int CLn = L - S;

  auto al = [](size_t n){ return (n + 255) & ~(size_t)255; };
  char* base = (char*)d_ws;
  size_t off = 0;
  auto take = [&](size_t n){ char* r = base + off; off += al(n); return r; };
  // persistent:
  unsigned short* xb  = (unsigned short*)take((size_t)S*DIMN*2);
  unsigned short* Wob = (unsigned short*)take((size_t)DIMN*DIMN*2);
  unsigned short* qb  = (unsigned short*)take((size_t)NH*S*HDIM*2);
  unsigned short* kb  = (unsigned short*)take((size_t)NH*L*HDIM*2);
  unsigned short* vtb = (unsigned short*)take((size_t)NH*HDIM*L*2);
  unsigned short* ob  = (unsigned short*)take((size_t)S*DIMN*2);
  const size_t ubase = off;
  // union pool A: transients (dead before attn): lin0/1/2 (bf16) + Wq/Wk/Wv (bf16)
  const size_t l_sz = al((size_t)S*DIMN*2);
  const size_t w_sz = al((size_t)DIMN*DIMN*2);
  unsigned short* lin0 = (unsigned short*)(base + ubase);
  unsigned short* lin1 = (unsigned short*)(base + ubase + l_sz);
  unsigned short* lin2 = (unsigned short*)(base + ubase + 2*l_sz);
  unsigned short* Wqb  = (unsigned short*)(base + ubase + 3*l_sz);
  unsigned short* Wkb  = (unsigned short*)(base + ubase + 3*l_sz + w_sz);
  unsigned short* Wvb  = (unsigned short*)(base + ubase + 3*l_sz + 2*w_sz);
  const size_t trans_sz = 3*l_sz + 3*w_sz;
  // union pool B: attention partials
  auto pool_sz = [&](int ns){
    return al((size_t)ns*NH*S*HDIM*4) + al((size_t)ns*NH*S*2*4);
  };
  int nsplit = 1;
  if (ubase + (trans_sz > pool_sz(4) ? trans_sz : pool_sz(4)) <= ws_size) nsplit = 4;
  else if (ubase + (trans_sz > pool_sz(2) ? trans_sz : pool_sz(2)) <= ws_size) nsplit = 2;
  if (ubase + trans_sz > ws_size) return;
  float* pacc = (float*)(base + ubase);
  float* pml  = (float*)(base + ubase + al((size_t)nsplit*NH*S*HDIM*4));

  const int wn8 = DIMN*DIMN/8;
  cast_bf16_kernel<<<(S*DIMN/8+255)/256, 256, 0, stream>>>(x,  xb,  S*DIMN/8);
  cast_bf16_kernel<<<(wn8+255)/256, 256, 0, stream>>>(Wq, Wqb, wn8);
  cast_bf16_kernel<<<(wn8+255)/256, 256, 0, stream>>>(Wk, Wkb, wn8);
  cast_bf16_kernel<<<(wn8+255)/256, 256, 0, stream>>>(Wv, Wvb, wn8);
  cast_bf16_kernel<<<(wn8+255)/256, 256, 0, stream>>>(Wo, Wob, wn8);
  kcache_kernel<<<CACHE_, 256, 0, stream>>>(k_cache, kb, CACHE_, L);
  vtrans_kernel<<<dim3((CACHE_+63)/64, 4, NH), 256, 0, stream>>>(v_cache, vtb, CACHE_, 0, L);

  const int mb = (S+127)/128;
  gemm_qkv<<<(DIMN/128)*mb*3, 256, 0, stream>>>(xb, Wqb, Wkb, Wvb, bq, bk, bv,
                                                lin0, lin1, lin2, S, DIMN, DIMN);
  const float qsc = 0.08838834764831845f * 1.4426950408889634f;
  norm_rope_kernel<<<S, 256, 0, stream>>>(lin0, gq, freqs, cur, qb, S, (size_t)S*HDIM, 0, qsc);
  norm_rope_kernel<<<S, 256, 0, stream>>>(lin1, gk, freqs, cur, kb, S, (size_t)L*HDIM, CACHE_, 1.0f);
  vtrans_bf16_kernel<<<dim3((S+63)/64, 4, NH), 256, 0, stream>>>(lin2, vtb, S, CACHE_, L);

  const int nx = (S+127)/128;
  attn_kernel<<<nx*NH*nsplit, 256, 0, stream>>>(qb, kb, vtb, ob,
                                                pacc, pml, S, L, CLn, nx, nsplit);
  if (nsplit > 1)
    combine_kernel<<<(S*NH+1)/2, 256, 0, stream>>>(pacc, pml, ob, S, nsplit);
  gemm_bt<<<(DIMN/128)*mb, 256, 0, stream>>>(ob, Wob, bo, (float*)d_out, S, DIMN, DIMN);
}

// Round 13
// 483.280 us; speedup vs baseline: 1.3641x; 1.0443x over previous
//
#include <hip/hip_runtime.h>

#define DIMN 2048
#define NH 16
#define HDIM 128

typedef __attribute__((ext_vector_type(4))) float f32x4;
typedef __attribute__((ext_vector_type(16))) float f32x16;
typedef __attribute__((ext_vector_type(8))) __bf16 bfx8;
typedef __attribute__((ext_vector_type(4))) __bf16 bf16x4;
typedef __attribute__((ext_vector_type(8))) unsigned short u16x8;

__device__ __forceinline__ unsigned short f2bf(float f){
  unsigned u = __builtin_bit_cast(unsigned, f);
  u += 0x7fffu + ((u >> 16) & 1u);
  return (unsigned short)(u >> 16);
}
__device__ __forceinline__ float bf2f(unsigned short h){
  unsigned u = (unsigned)h << 16;
  return __builtin_bit_cast(float, u);
}

__device__ __forceinline__ void gl_lds16(const void* g, void* l){
  __builtin_amdgcn_global_load_lds((const __attribute__((address_space(1))) void*)g,
                                   (__attribute__((address_space(3))) void*)l, 16, 0, 0);
}

// m204 bijective XCD-chunked remap (works for any nwg)
__device__ __forceinline__ int xcd_swz(int bid, int nwg){
  const int q = nwg >> 3, r = nwg & 7;
  const int xcd = bid & 7, idx = bid >> 3;
  return (xcd < r ? xcd*(q+1) : r*(q+1) + (xcd-r)*q) + idx;
}

#define MFMA16(a,b,c) __builtin_amdgcn_mfma_f32_16x16x32_bf16((a),(b),(c),0,0,0)
#define MFMA32(a,b,c) __builtin_amdgcn_mfma_f32_32x32x16_bf16((a),(b),(c),0,0,0)

// ---------------- elementwise f32 -> bf16 cast ----------------
__global__ __launch_bounds__(256) void cast_bf16_kernel(const float* __restrict__ in,
                                                        unsigned short* __restrict__ out, int n8){
  int i = blockIdx.x*256 + threadIdx.x;
  if (i >= n8) return;
  const float4* p = (const float4*)(in + (size_t)i*8);
  float4 a = p[0], b = p[1];
  u16x8 o;
  o[0]=f2bf(a.x); o[1]=f2bf(a.y); o[2]=f2bf(a.z); o[3]=f2bf(a.w);
  o[4]=f2bf(b.x); o[5]=f2bf(b.y); o[6]=f2bf(b.z); o[7]=f2bf(b.w);
  *(u16x8*)(out + (size_t)i*8) = o;
}

// ---------------- k_cache (CACHE,H,HD) f32 -> kb[h][k][d] bf16 ----------------
__global__ __launch_bounds__(256) void kcache_kernel(const float* __restrict__ kc,
                                                     unsigned short* __restrict__ kb,
                                                     int R, int L_){
  const int gid = blockIdx.x*256 + threadIdx.x;
  if (gid >= R*256) return;
  const size_t idx = (size_t)gid * 8;
  const int k   = (int)(idx >> 11);
  const int rem = (int)(idx & 2047);
  const int hh  = rem >> 7, d = rem & 127;
  const float4* p = (const float4*)(kc + idx);
  float4 a = p[0], b = p[1];
  u16x8 o;
  o[0]=f2bf(a.x); o[1]=f2bf(a.y); o[2]=f2bf(a.z); o[3]=f2bf(a.w);
  o[4]=f2bf(b.x); o[5]=f2bf(b.y); o[6]=f2bf(b.z); o[7]=f2bf(b.w);
  *(u16x8*)(kb + (size_t)hh*L_*HDIM + (size_t)k*HDIM + d) = o;
}

// ---------------- (R,H,HD) f32 -> vt[h][d][koff+k] bf16 (transpose) ----------------
__global__ __launch_bounds__(256) void vtrans_kernel(const float* __restrict__ src,
                                                     unsigned short* __restrict__ vt,
                                                     int R, int koff, int L_){
  __shared__ __align__(16) unsigned short tile[32][72];
  const int kb0 = blockIdx.x * 64, db0 = blockIdx.y * 32, hh = blockIdx.z;
  const int t = threadIdx.x;
  const int kk = t >> 2, dd = (t & 3) * 8;
  const int k = kb0 + kk;
  if (k < R){
    const float* p = src + (size_t)k*DIMN + hh*HDIM + db0 + dd;
    float4 a = ((const float4*)p)[0], b = ((const float4*)p)[1];
    tile[dd+0][kk] = f2bf(a.x); tile[dd+1][kk] = f2bf(a.y);
    tile[dd+2][kk] = f2bf(a.z); tile[dd+3][kk] = f2bf(a.w);
    tile[dd+4][kk] = f2bf(b.x); tile[dd+5][kk] = f2bf(b.y);
    tile[dd+6][kk] = f2bf(b.z); tile[dd+7][kk] = f2bf(b.w);
  }
  __syncthreads();
  const int d = t >> 3, k0 = (t & 7) * 8;
  unsigned short* dst = vt + (size_t)hh*HDIM*L_ + (size_t)(db0+d)*L_ + koff + kb0 + k0;
  if (kb0 + k0 + 8 <= R){
    *(u16x8*)dst = *(const u16x8*)&tile[d][k0];
  } else {
    #pragma unroll
    for (int e=0;e<8;++e) if (kb0 + k0 + e < R) dst[e] = tile[d][k0+e];
  }
}

// ---------------- same but bf16 source (projected V) ----------------
__global__ __launch_bounds__(256) void vtrans_bf16_kernel(const unsigned short* __restrict__ src,
    unsigned short* __restrict__ vt, int R, int koff, int L_){
  __shared__ __align__(16) unsigned short tile[32][72];
  const int kb0 = blockIdx.x * 64, db0 = blockIdx.y * 32, hh = blockIdx.z;
  const int t = threadIdx.x;
  const int kk = t >> 2, dd = (t & 3) * 8;
  const int k = kb0 + kk;
  if (k < R){
    u16x8 a = *(const u16x8*)(src + (size_t)k*DIMN + hh*HDIM + db0 + dd);
    #pragma unroll
    for (int e=0;e<8;++e) tile[dd+e][kk] = a[e];
  }
  __syncthreads();
  const int d = t >> 3, k0 = (t & 7) * 8;
  unsigned short* dst = vt + (size_t)hh*HDIM*L_ + (size_t)(db0+d)*L_ + koff + kb0 + k0;
  if (kb0 + k0 + 8 <= R){
    *(u16x8*)dst = *(const u16x8*)&tile[d][k0];
  } else {
    #pragma unroll
    for (int e=0;e<8;++e) if (kb0 + k0 + e < R) dst[e] = tile[d][k0+e];
  }
}

// ---------------- fused rmsnorm + interleaved RoPE (bf16 in), bf16 head-major out ----
__global__ __launch_bounds__(256) void norm_rope_kernel(const unsigned short* __restrict__ lin,
    const float* __restrict__ g, const float* __restrict__ freqs, const int* __restrict__ cur,
    unsigned short* __restrict__ out, int S_, size_t head_stride, int row_off, float oscale){
  const int q = blockIdx.x, t = threadIdx.x;
  u16x8 v = *(const u16x8*)(lin + (size_t)q*DIMN + t*8);
  float x[8];
  #pragma unroll
  for (int e=0;e<8;++e) x[e] = bf2f(v[e]);
  float ss = 0.f;
  #pragma unroll
  for (int e=0;e<8;++e) ss += x[e]*x[e];
  for (int m=1;m<64;m<<=1) ss += __shfl_xor(ss, m);
  __shared__ float red[4];
  if ((t & 63) == 0) red[t>>6] = ss;
  __syncthreads();
  const float tot = red[0]+red[1]+red[2]+red[3];
  const float rstd = rsqrtf(tot * (1.0f/2048.0f) + 1e-6f);
  const int n0 = t*8;
  float xr[8];
  #pragma unroll
  for (int e=0;e<8;++e) xr[e] = x[e] * rstd * g[n0+e];
  const int pos = cur[0] + q;
  const int hh = n0 >> 7, d0 = n0 & 127;
  const float* fr = freqs + (size_t)pos * HDIM;
  float o[8];
  #pragma unroll
  for (int p=0;p<4;++p){
    const int j = (d0>>1) + p;
    const float c = fr[j], s = fr[64+j];
    o[2*p]   = xr[2*p]*c - xr[2*p+1]*s;
    o[2*p+1] = xr[2*p+1]*c + xr[2*p]*s;
  }
  u16x8 ov;
  #pragma unroll
  for (int e=0;e<8;++e) ov[e] = f2bf(o[e]*oscale);
  *(u16x8*)(out + (size_t)hh*head_stride + (size_t)(q+row_off)*HDIM + d0) = ov;
}

// ---------------- C[M,N] = A[M,K] * B[N,K]^T + bias, bf16 in fp32 out ----------------
// 1D grid + XCD swizzle; DOUBLE-BUFFERED gl_lds staging, one barrier per K-step.
__global__ __launch_bounds__(256,2) void gemm_bt(const unsigned short* __restrict__ A,
    const unsigned short* __restrict__ B, const float* __restrict__ bias,
    float* __restrict__ C, int M, int N, int K){
  __shared__ __align__(16) unsigned short As[2][128*64];
  __shared__ __align__(16) unsigned short Bs[2][128*64];
  const int mb = (M + 127) >> 7;
  const int swz = xcd_swz(blockIdx.x, gridDim.x);
  const int bx = swz / mb, by = swz % mb;
  const int t = threadIdx.x;
  const int w = t >> 6, lane = t & 63, lh = lane >> 4, ll = lane & 15;
  const int wr = w >> 1, wc = w & 1;
  const int m0 = by * 128, n0 = bx * 128;
  const int srow = t >> 3;
  const int scb  = (t & 7) * 16;
  const int swc  = (scb ^ ((srow & 7) << 4)) >> 1;
  int arow[4]; size_t brow[4];
  #pragma unroll
  for (int c=0;c<4;++c){
    int r = m0 + c*32 + srow; if (r >= M) r = M-1;
    arow[c] = r;
    brow[c] = (size_t)(n0 + c*32 + srow);
  }
  const int xsw = (ll & 7) << 4;
  f32x4 acc[4][4] = {};
  const int nk = K >> 6;
  auto stage = [&](int b, int kt){
    const int k0 = kt << 6;
    #pragma unroll
    for (int c=0;c<4;++c){
      gl_lds16(A + (size_t)arow[c]*K + k0 + swc, (char*)As[b] + c*4096 + w*1024);
      gl_lds16(B + brow[c]*K       + k0 + swc, (char*)Bs[b] + c*4096 + w*1024);
    }
  };
  stage(0, 0);
  asm volatile("s_waitcnt vmcnt(0)" ::: "memory");
  __syncthreads();
  int cur = 0;
  for (int kt = 0; kt < nk; ++kt){
    if (kt + 1 < nk) stage(cur ^ 1, kt + 1);
    #pragma unroll
    for (int kk=0;kk<2;++kk){
      const int cb = kk*64 + lh*16;
      bfx8 a[4], b[4];
      #pragma unroll
      for (int i=0;i<4;++i)
        a[i] = *(const bfx8*)((const char*)As[cur] + (wr*64 + i*16 + ll)*128 + (cb ^ xsw));
      #pragma unroll
      for (int j=0;j<4;++j)
        b[j] = *(const bfx8*)((const char*)Bs[cur] + (wc*64 + j*16 + ll)*128 + (cb ^ xsw));
      __builtin_amdgcn_s_setprio(1);
      #pragma unroll
      for (int i=0;i<4;++i)
        #pragma unroll
        for (int j=0;j<4;++j)
          acc[i][j] = MFMA16(a[i], b[j], acc[i][j]);
      __builtin_amdgcn_s_setprio(0);
    }
    asm volatile("s_waitcnt vmcnt(0)" ::: "memory");
    __syncthreads();
    cur ^= 1;
  }
  #pragma unroll
  for (int i=0;i<4;++i){
    #pragma unroll
    for (int j=0;j<4;++j){
      const int col = n0 + wc*64 + j*16 + ll;
      const float bb = bias[col];
      #pragma unroll
      for (int r=0;r<4;++r){
        const int row = m0 + wr*64 + i*16 + lh*4 + r;
        if (row < M) C[(size_t)row*N + col] = acc[i][j][r] + bb;
      }
    }
  }
}

// ---------------- fused QKV gemm (1D grid + XCD swizzle); dbuf; bf16 out ----------------
__global__ __launch_bounds__(256,2) void gemm_qkv(const unsigned short* __restrict__ A,
    const unsigned short* __restrict__ B0, const unsigned short* __restrict__ B1,
    const unsigned short* __restrict__ B2, const float* __restrict__ g0,
    const float* __restrict__ g1, const float* __restrict__ g2,
    unsigned short* __restrict__ C0, unsigned short* __restrict__ C1,
    unsigned short* __restrict__ C2, int M, int N, int K){
  const int mb = (M + 127) >> 7;
  const int nxt = N >> 7;
  const int per = nxt * mb;
  const int swz = xcd_swz(blockIdx.x, gridDim.x);
  const int zz = swz / per;
  const int rem = swz - zz * per;
  const int bx = rem / mb, by = rem % mb;
  const unsigned short* B = (zz==0) ? B0 : (zz==1) ? B1 : B2;
  const float* bias       = (zz==0) ? g0 : (zz==1) ? g1 : g2;
  unsigned short* C       = (zz==0) ? C0 : (zz==1) ? C1 : C2;
  __shared__ __align__(16) unsigned short As[2][128*64];
  __shared__ __align__(16) unsigned short Bs[2][128*64];
  const int t = threadIdx.x;
  const int w = t >> 6, lane = t & 63, lh = lane >> 4, ll = lane & 15;
  const int wr = w >> 1, wc = w & 1;
  const int m0 = by * 128, n0 = bx * 128;
  const int srow = t >> 3;
  const int scb  = (t & 7) * 16;
  const int swc  = (scb ^ ((srow & 7) << 4)) >> 1;
  int arow[4]; size_t brow[4];
  #pragma unroll
  for (int c=0;c<4;++c){
    int r = m0 + c*32 + srow; if (r >= M) r = M-1;
    arow[c] = r;
    brow[c] = (size_t)(n0 + c*32 + srow);
  }
  const int xsw = (ll & 7) << 4;
  f32x4 acc[4][4] = {};
  const int nk = K >> 6;
  auto stage = [&](int b, int kt){
    const int k0 = kt << 6;
    #pragma unroll
    for (int c=0;c<4;++c){
      gl_lds16(A + (size_t)arow[c]*K + k0 + swc, (char*)As[b] + c*4096 + w*1024);
      gl_lds16(B + brow[c]*K       + k0 + swc, (char*)Bs[b] + c*4096 + w*1024);
    }
  };
  stage(0, 0);
  asm volatile("s_waitcnt vmcnt(0)" ::: "memory");
  __syncthreads();
  int cur = 0;
  for (int kt = 0; kt < nk; ++kt){
    if (kt + 1 < nk) stage(cur ^ 1, kt + 1);
    #pragma unroll
    for (int kk=0;kk<2;++kk){
      const int cb = kk*64 + lh*16;
      bfx8 a[4], b[4];
      #pragma unroll
      for (int i=0;i<4;++i)
        a[i] = *(const bfx8*)((const char*)As[cur] + (wr*64 + i*16 + ll)*128 + (cb ^ xsw));
      #pragma unroll
      for (int j=0;j<4;++j)
        b[j] = *(const bfx8*)((const char*)Bs[cur] + (wc*64 + j*16 + ll)*128 + (cb ^ xsw));
      __builtin_amdgcn_s_setprio(1);
      #pragma unroll
      for (int i=0;i<4;++i)
        #pragma unroll
        for (int j=0;j<4;++j)
          acc[i][j] = MFMA16(a[i], b[j], acc[i][j]);
      __builtin_amdgcn_s_setprio(0);
    }
    asm volatile("s_waitcnt vmcnt(0)" ::: "memory");
    __syncthreads();
    cur ^= 1;
  }
  #pragma unroll
  for (int i=0;i<4;++i){
    #pragma unroll
    for (int j=0;j<4;++j){
      const int col = n0 + wc*64 + j*16 + ll;
      const float bb = bias[col];
      #pragma unroll
      for (int r=0;r<4;++r){
        const int row = m0 + wr*64 + i*16 + lh*4 + r;
        if (row < M) C[(size_t)row*N + col] = f2bf(acc[i][j][r] + bb);
      }
    }
  }
}

// ---------------- flash attention: 4 waves, 32x32x16 MFMA, gl_lds dbuf staging --------
// R11/R12 structure with staging via global_load_lds (linear LDS dest, per-lane
// pre-swizzled source col — rule #21c, same as the gemms). Removes 8 ds_write_b128
// + 8 VMEM reg-returns + ~32 staging VGPRs per wave. One vmcnt(0)+barrier per tile,
// DMA of tile kt+1 issued before compute on kt (covered by QK^T+softmax+PV).
// No clamping needed: all staged keys < L by causality; V col swizzle stays in-row.
__global__ __launch_bounds__(256,2) void attn_kernel(const unsigned short* __restrict__ Q,
    const unsigned short* __restrict__ K, const unsigned short* __restrict__ VT,
    unsigned short* __restrict__ O, float* __restrict__ pacc, float* __restrict__ pml,
    int S_, int L_, int CLn, int nx, int nsplit){
  __shared__ __align__(16) unsigned short Ks[2][64*128];
  __shared__ __align__(16) unsigned short Vs[2][128*64];
  __shared__ __align__(16) unsigned short Ps[4][32*64];
  const int nwg = gridDim.x;
  const int swzid = (blockIdx.x & 7)*(nwg >> 3) + (blockIdx.x >> 3);
  const int xq = swzid % nx;
  const int rest = swzid / nx;
  const int hh = rest % NH;
  const int z  = rest / NH;
  const int q0 = xq * 128;
  const int t = threadIdx.x, w = t >> 6, lane = t & 63;
  const int l31 = lane & 31, h = lane >> 5;
  char* Pw = (char*)Ps[w];
  const int xswp = (l31 & 7) << 4;
  const unsigned short* Qh = Q  + (size_t)hh*S_*HDIM;
  const unsigned short* Kh = K  + (size_t)hh*L_*HDIM;
  const unsigned short* Vh = VT + (size_t)hh*HDIM*L_;
  const int wrow0 = q0 + w*32;
  const int myq = wrow0 + l31;            // this lane's q-row (state + QK^T col)
  bfx8 qf[8];
  {
    int qr = myq; if (qr >= S_) qr = S_ - 1;
    #pragma unroll
    for (int kk=0;kk<8;++kk)
      qf[kk] = *(const bfx8*)(Qh + (size_t)qr*HDIM + kk*16 + h*8);
  }
  f32x16 acc[4] = {};                     // [db]: O[q(reg,h)][db*32 + l31]
  float m_st = -1e20f, l_st = 0.f;
  int qlast = q0 + 127; if (qlast >= S_) qlast = S_ - 1;
  const int kend = CLn + qlast + 1;
  const int nt = (kend + 63) >> 6;
  const int tps = (nt + nsplit - 1) / nsplit;
  const int t0 = z * tps;
  int t1 = t0 + tps; if (t1 > nt) t1 = nt;
  // staging geometry: K rows 256B (16 lanes/row), V rows 128B (8 lanes/row)
  const int ksrow = t >> 4;
  const int kswc  = (((t & 15)*16) ^ ((ksrow & 7) << 4)) >> 1;  // pre-swizzled src col (shorts)
  const int vsrow = t >> 3;
  const int vswc  = (((t & 7)*16) ^ ((vsrow & 7) << 4)) >> 1;

  auto stage = [&](int b, int ktile){
    const int kv0 = ktile << 6;
    #pragma unroll
    for (int c=0;c<4;++c)
      gl_lds16(Kh + (size_t)(kv0 + c*16 + ksrow)*HDIM + kswc, (char*)Ks[b] + c*4096 + w*1024);
    #pragma unroll
    for (int c=0;c<4;++c)
      gl_lds16(Vh + (size_t)(c*32 + vsrow)*L_ + kv0 + vswc, (char*)Vs[b] + c*4096 + w*1024);
  };

  if (t0 < t1) stage(0, t0);
  asm volatile("s_waitcnt vmcnt(0)" ::: "memory");
  __syncthreads();
  const int krow0 = l31,      koff0 = (krow0 & 7) << 4;   // j=0 K rows
  const int krow1 = 32 + l31, koff1 = (krow1 & 7) << 4;   // j=1 K rows
  int cur = 0;
  for (int kt = t0; kt < t1; ++kt){
    const int kv0 = kt << 6;
    if (kt + 1 < t1) stage(cur ^ 1, kt + 1);   // DMA next tile; covered by compute
    const char* Kc = (const char*)Ks[cur];
    const char* Vc = (const char*)Vs[cur];
    // QK^T: sc_j[reg] = S[k = kv0 + 32j + (reg&3)+8*(reg>>2)+4h][q = myq]
    f32x16 sc0 = {}, sc1 = {};
    __builtin_amdgcn_s_setprio(1);
    #pragma unroll
    for (int kk=0;kk<8;++kk){
      const int cb = kk*32 + h*16;
      bfx8 kf0 = *(const bfx8*)(Kc + krow0*256 + (cb ^ koff0));
      bfx8 kf1 = *(const bfx8*)(Kc + krow1*256 + (cb ^ koff1));
      sc0 = MFMA32(kf0, qf[kk], sc0);
      sc1 = MFMA32(kf1, qf[kk], sc1);
    }
    __builtin_amdgcn_s_setprio(0);
    // causal mask (scale*log2e folded into Q)
    if (kv0 + 63 > CLn + wrow0){
      const int lim = CLn + myq;
      #pragma unroll
      for (int r=0;r<16;++r){
        const int kl = (r&3) + 8*(r>>2) + 4*h;
        if (kv0 + kl      > lim) sc0[r] = -1e30f;
        if (kv0 + 32 + kl > lim) sc1[r] = -1e30f;
      }
    }
    // row max: 31 in-lane fmax + cross-half
    float mt = sc0[0];
    #pragma unroll
    for (int r=1;r<16;++r) mt = fmaxf(mt, sc0[r]);
    #pragma unroll
    for (int r=0;r<16;++r) mt = fmaxf(mt, sc1[r]);
    mt = fmaxf(mt, __shfl_xor(mt, 32));
    mt = fmaxf(mt, -1e20f);
    if (!__all(mt - m_st <= 11.54f)){   // defer-max (8 nats, log2 domain)
      const float mn = fmaxf(m_st, mt);
      const float corr = exp2f(m_st - mn);
      m_st = mn;
      l_st *= corr;
      #pragma unroll
      for (int r=0;r<16;++r){
        const int qrow = (r&3) + 8*(r>>2) + 4*h;
        const float ca = __shfl(corr, qrow);
        #pragma unroll
        for (int db=0;db<4;++db) acc[db][r] *= ca;
      }
    }
    // P = exp2(sc - m), row sum (in-lane + cross-half)
    float rs = 0.f;
    #pragma unroll
    for (int r=0;r<16;++r){
      const float p0 = exp2f(sc0[r] - m_st);
      const float p1 = exp2f(sc1[r] - m_st);
      sc0[r] = p0; sc1[r] = p1;
      rs += p0 + p1;
    }
    rs += __shfl_xor(rs, 32);
    l_st += rs;
    // P -> wave-private LDS, b64 writes: regs r=4i+j -> k = 8i+4h+j (adjacent j)
    #pragma unroll
    for (int i=0;i<4;++i){
      bf16x4 p0 = { (__bf16)sc0[4*i], (__bf16)sc0[4*i+1], (__bf16)sc0[4*i+2], (__bf16)sc0[4*i+3] };
      bf16x4 p1 = { (__bf16)sc1[4*i], (__bf16)sc1[4*i+1], (__bf16)sc1[4*i+2], (__bf16)sc1[4*i+3] };
      const int kb0b = (8*i + 4*h) * 2;          // byte offset of k within P row
      *(bf16x4*)(Pw + l31*128 + (kb0b        ^ xswp)) = p0;
      *(bf16x4*)(Pw + l31*128 + ((64 + kb0b) ^ xswp)) = p1;
    }
    // PV: A-frag read back (P[q=l31][k = s*16 + h*8 + e]), B = V^T frag
    __builtin_amdgcn_s_setprio(1);
    #pragma unroll
    for (int s=0;s<4;++s){
      bfx8 pa = *(const bfx8*)(Pw + l31*128 + ((s*32 + h*16) ^ xswp));
      const int vb = s*32 + h*16;
      #pragma unroll
      for (int db=0;db<4;++db){
        const int vrow = db*32 + l31;
        bfx8 vf = *(const bfx8*)(Vc + vrow*128 + (vb ^ ((vrow & 7) << 4)));
        acc[db] = MFMA32(pa, vf, acc[db]);
      }
    }
    __builtin_amdgcn_s_setprio(0);
    asm volatile("s_waitcnt vmcnt(0)" ::: "memory");   // next-tile DMA landed
    __syncthreads();                                   // all waves done with buf[cur]
    cur ^= 1;
  }
  // epilogue: acc row q = wrow0 + (reg&3)+8*(reg>>2)+4h, col d = db*32 + l31
  if (nsplit == 1){
    const float linv = 1.0f / l_st;
    #pragma unroll
    for (int r=0;r<16;++r){
      const int qrow = (r&3) + 8*(r>>2) + 4*h;
      const float inv = __shfl(linv, qrow);
      const int qr = wrow0 + qrow;
      if (qr < S_){
        #pragma unroll
        for (int db=0;db<4;++db)
          O[(size_t)qr*DIMN + hh*HDIM + db*32 + l31] = f2bf(acc[db][r]*inv);
      }
    }
  } else {
    #pragma unroll
    for (int r=0;r<16;++r){
      const int qrow = (r&3) + 8*(r>>2) + 4*h;
      const int qr = wrow0 + qrow;
      if (qr < S_){
        const size_t rid = ((size_t)z*NH + hh)*S_ + qr;
        float* dst = pacc + rid*128;
        #pragma unroll
        for (int db=0;db<4;++db) dst[db*32 + l31] = acc[db][r];
      }
    }
    if (lane < 32 && myq < S_){
      const size_t rid2 = ((size_t)z*NH + hh)*S_ + myq;
      pml[rid2*2]   = m_st;
      pml[rid2*2+1] = l_st;
    }
  }
}

// ---------------- combine partials -> ob bf16 (exp2 domain m) ----------------
__global__ __launch_bounds__(256) void combine_kernel(const float* __restrict__ pacc,
    const float* __restrict__ pml, unsigned short* __restrict__ ob, int S_, int nsplit){
  const int t = threadIdx.x;
  const int rid = blockIdx.x*2 + (t >> 7);   // hh*S_+q
  if (rid >= S_*NH) return;
  const int d = t & 127;
  const int hh = rid / S_;
  const int q  = rid - hh*S_;
  float M = -1e20f;
  for (int s=0; s<nsplit; ++s)
    M = fmaxf(M, pml[((size_t)s*NH*S_ + rid)*2]);
  float lt = 0.f, o = 0.f;
  for (int s=0; s<nsplit; ++s){
    const float m = pml[((size_t)s*NH*S_ + rid)*2];
    const float l = pml[((size_t)s*NH*S_ + rid)*2 + 1];
    const float wgt = exp2f(m - M);
    lt += l * wgt;
    o  += pacc[((size_t)s*NH*S_ + rid)*128 + d] * wgt;
  }
  if (lt == 0.f) lt = 1.f;
  ob[(size_t)q*DIMN + hh*HDIM + d] = f2bf(o / lt);
}

extern "C" void kernel_launch(void* const* d_in, const int* in_sizes, int n_in,
                              void* d_out, int out_size, void* d_ws, size_t ws_size,
                              hipStream_t stream){
  const float* x       = (const float*)d_in[0];
  const float* freqs   = (const float*)d_in[1];
  const float* k_cache = (const float*)d_in[2];
  const float* v_cache = (const float*)d_in[3];
  const float* Wq = (const float*)d_in[4];
  const float* bq = (const float*)d_in[5];
  const float* Wk = (const float*)d_in[6];
  const float* bk = (const float*)d_in[7];
  const float* Wv = (const float*)d_in[8];
  const float* bv = (const float*)d_in[9];
  const float* Wo = (const float*)d_in[10];
  const float* bo = (const float*)d_in[11];
  const float* gq = (const float*)d_in[12];
  const float* gk = (const float*)d_in[13];
  const int*   cur = (const int*)d_in[14];

  const int S = in_sizes[0] / DIMN;
  const int CACHE_ = in_sizes[2] / DIMN;
  const int L = CACHE_ + S;
  const int CLn = L - S;

  auto al = [](size_t n){ return (n + 255) & ~(size_t)255; };
  char* base = (char*)d_ws;
  size_t off = 0;
  auto take = [&](size_t n){ char* r = base + off; off += al(n); return r; };
  // persistent:
  unsigned short* xb  = (unsigned short*)take((size_t)S*DIMN*2);
  unsigned short* Wob = (unsigned short*)take((size_t)DIMN*DIMN*2);
  unsigned short* qb  = (unsigned short*)take((size_t)NH*S*HDIM*2);
  unsigned short* kb  = (unsigned short*)take((size_t)NH*L*HDIM*2);
  unsigned short* vtb = (unsigned short*)take((size_t)NH*HDIM*L*2);
  unsigned short* ob  = (unsigned short*)take((size_t)S*DIMN*2);
  const size_t ubase = off;
  // union pool A: transients (dead before attn): lin0/1/2 (bf16) + Wq/Wk/Wv (bf16)
  const size_t l_sz = al((size_t)S*DIMN*2);
  const size_t w_sz = al((size_t)DIMN*DIMN*2);
  unsigned short* lin0 = (unsigned short*)(base + ubase);
  unsigned short* lin1 = (unsigned short*)(base + ubase + l_sz);
  unsigned short* lin2 = (unsigned short*)(base + ubase + 2*l_sz);
  unsigned short* Wqb  = (unsigned short*)(base + ubase + 3*l_sz);
  unsigned short* Wkb  = (unsigned short*)(base + ubase + 3*l_sz + w_sz);
  unsigned short* Wvb  = (unsigned short*)(base + ubase + 3*l_sz + 2*w_sz);
  const size_t trans_sz = 3*l_sz + 3*w_sz;
  // union pool B: attention partials
  auto pool_sz = [&](int ns){
    return al((size_t)ns*NH*S*HDIM*4) + al((size_t)ns*NH*S*2*4);
  };
  int nsplit = 1;
  if (ubase + (trans_sz > pool_sz(4) ? trans_sz : pool_sz(4)) <= ws_size) nsplit = 4;
  else if (ubase + (trans_sz > pool_sz(2) ? trans_sz : pool_sz(2)) <= ws_size) nsplit = 2;
  if (ubase + trans_sz > ws_size) return;
  float* pacc = (float*)(base + ubase);
  float* pml  = (float*)(base + ubase + al((size_t)nsplit*NH*S*HDIM*4));

  const int wn8 = DIMN*DIMN/8;
  cast_bf16_kernel<<<(S*DIMN/8+255)/256, 256, 0, stream>>>(x,  xb,  S*DIMN/8);
  cast_bf16_kernel<<<(wn8+255)/256, 256, 0, stream>>>(Wq, Wqb, wn8);
  cast_bf16_kernel<<<(wn8+255)/256, 256, 0, stream>>>(Wk, Wkb, wn8);
  cast_bf16_kernel<<<(wn8+255)/256, 256, 0, stream>>>(Wv, Wvb, wn8);
  cast_bf16_kernel<<<(wn8+255)/256, 256, 0, stream>>>(Wo, Wob, wn8);
  kcache_kernel<<<CACHE_, 256, 0, stream>>>(k_cache, kb, CACHE_, L);
  vtrans_kernel<<<dim3((CACHE_+63)/64, 4, NH), 256, 0, stream>>>(v_cache, vtb, CACHE_, 0, L);

  const int mb = (S+127)/128;
  gemm_qkv<<<(DIMN/128)*mb*3, 256, 0, stream>>>(xb, Wqb, Wkb, Wvb, bq, bk, bv,
                                                lin0, lin1, lin2, S, DIMN, DIMN);
  const float qsc = 0.08838834764831845f * 1.4426950408889634f;
  norm_rope_kernel<<<S, 256, 0, stream>>>(lin0, gq, freqs, cur, qb, S, (size_t)S*HDIM, 0, qsc);
  norm_rope_kernel<<<S, 256, 0, stream>>>(lin1, gk, freqs, cur, kb, S, (size_t)L*HDIM, CACHE_, 1.0f);
  vtrans_bf16_kernel<<<dim3((S+63)/64, 4, NH), 256, 0, stream>>>(lin2, vtb, S, CACHE_, L);

  const int nx = (S+127)/128;
  attn_kernel<<<nx*NH*nsplit, 256, 0, stream>>>(qb, kb, vtb, ob,
                                                pacc, pml, S, L, CLn, nx, nsplit);
  if (nsplit > 1)
    combine_kernel<<<(S*NH+1)/2, 256, 0, stream>>>(pacc, pml, ob, S, nsplit);
  gemm_bt<<<(DIMN/128)*mb, 256, 0, stream>>>(ob, Wob, bo, (float*)d_out, S, DIMN, DIMN);
}

// Round 14
// 467.550 us; speedup vs baseline: 1.4100x; 1.0336x over previous
//
#include <hip/hip_runtime.h>

#define DIMN 2048
#define NH 16
#define HDIM 128

typedef __attribute__((ext_vector_type(4))) float f32x4;
typedef __attribute__((ext_vector_type(16))) float f32x16;
typedef __attribute__((ext_vector_type(8))) __bf16 bfx8;
typedef __attribute__((ext_vector_type(4))) __bf16 bf16x4;
typedef __attribute__((ext_vector_type(8))) unsigned short u16x8;

__device__ __forceinline__ unsigned short f2bf(float f){
  unsigned u = __builtin_bit_cast(unsigned, f);
  u += 0x7fffu + ((u >> 16) & 1u);
  return (unsigned short)(u >> 16);
}
__device__ __forceinline__ float bf2f(unsigned short h){
  unsigned u = (unsigned)h << 16;
  return __builtin_bit_cast(float, u);
}

__device__ __forceinline__ void gl_lds16(const void* g, void* l){
  __builtin_amdgcn_global_load_lds((const __attribute__((address_space(1))) void*)g,
                                   (__attribute__((address_space(3))) void*)l, 16, 0, 0);
}

// m204 bijective XCD-chunked remap (works for any nwg)
__device__ __forceinline__ int xcd_swz(int bid, int nwg){
  const int q = nwg >> 3, r = nwg & 7;
  const int xcd = bid & 7, idx = bid >> 3;
  return (xcd < r ? xcd*(q+1) : r*(q+1) + (xcd-r)*q) + idx;
}

#define MFMA16(a,b,c) __builtin_amdgcn_mfma_f32_16x16x32_bf16((a),(b),(c),0,0,0)
#define MFMA32(a,b,c) __builtin_amdgcn_mfma_f32_32x32x16_bf16((a),(b),(c),0,0,0)

// ---------------- merged prep: casts + kcache relayout + v_cache transpose ----------
// sections by blockIdx.x range (block-uniform): [0,S) x-cast; [S,S+4*2048) W casts;
// [.., +CACHE) kcache; [.., +nkb*4*NH) vtrans of v_cache.
__global__ __launch_bounds__(256) void prep_kernel(const float* __restrict__ x,
    const float* __restrict__ Wq, const float* __restrict__ Wk, const float* __restrict__ Wv,
    const float* __restrict__ Wo, const float* __restrict__ k_cache,
    const float* __restrict__ v_cache,
    unsigned short* __restrict__ xb, unsigned short* __restrict__ Wqb,
    unsigned short* __restrict__ Wkb, unsigned short* __restrict__ Wvb,
    unsigned short* __restrict__ Wob, unsigned short* __restrict__ kb,
    unsigned short* __restrict__ vtb, int S_, int CACHE_, int L_){
  __shared__ __align__(16) unsigned short tile[32][72];
  const int WB = (DIMN*DIMN/8)/256;   // 2048 blocks per weight
  const int t = threadIdx.x;
  int bid = blockIdx.x;
  if (bid < S_){
    // ---- x cast: one block per row ----
    const size_t base = (size_t)bid*DIMN + t*8;
    const float4* p = (const float4*)(x + base);
    float4 a = p[0], b = p[1];
    u16x8 o;
    o[0]=f2bf(a.x); o[1]=f2bf(a.y); o[2]=f2bf(a.z); o[3]=f2bf(a.w);
    o[4]=f2bf(b.x); o[5]=f2bf(b.y); o[6]=f2bf(b.z); o[7]=f2bf(b.w);
    *(u16x8*)(xb + base) = o;
    return;
  }
  bid -= S_;
  if (bid < 4*WB){
    // ---- weight casts ----
    const int wsel = bid / WB;
    const int lb   = bid - wsel*WB;
    const float* in = (wsel==0) ? Wq : (wsel==1) ? Wk : (wsel==2) ? Wv : Wo;
    unsigned short* out = (wsel==0) ? Wqb : (wsel==1) ? Wkb : (wsel==2) ? Wvb : Wob;
    const size_t base = ((size_t)lb*256 + t)*8;
    const float4* p = (const float4*)(in + base);
    float4 a = p[0], b = p[1];
    u16x8 o;
    o[0]=f2bf(a.x); o[1]=f2bf(a.y); o[2]=f2bf(a.z); o[3]=f2bf(a.w);
    o[4]=f2bf(b.x); o[5]=f2bf(b.y); o[6]=f2bf(b.z); o[7]=f2bf(b.w);
    *(u16x8*)(out + base) = o;
    return;
  }
  bid -= 4*WB;
  if (bid < CACHE_){
    // ---- kcache relayout: one block per key row ----
    const size_t idx = ((size_t)bid*256 + t)*8;
    const int k   = (int)(idx >> 11);
    const int rem = (int)(idx & 2047);
    const int hh  = rem >> 7, d = rem & 127;
    const float4* p = (const float4*)(k_cache + idx);
    float4 a = p[0], b = p[1];
    u16x8 o;
    o[0]=f2bf(a.x); o[1]=f2bf(a.y); o[2]=f2bf(a.z); o[3]=f2bf(a.w);
    o[4]=f2bf(b.x); o[5]=f2bf(b.y); o[6]=f2bf(b.z); o[7]=f2bf(b.w);
    *(u16x8*)(kb + (size_t)hh*L_*HDIM + (size_t)k*HDIM + d) = o;
    return;
  }
  bid -= CACHE_;
  {
    // ---- v_cache transpose -> vt[h][d][k] ----
    const int nkb = (CACHE_ + 63) >> 6;
    const int kbi = bid % nkb;
    const int rest = bid / nkb;
    const int dbi = rest & 3;
    const int hh  = rest >> 2;
    const int kb0 = kbi * 64, db0 = dbi * 32;
    const int kk = t >> 2, dd = (t & 3) * 8;
    const int k = kb0 + kk;
    if (k < CACHE_){
      const float* p = v_cache + (size_t)k*DIMN + hh*HDIM + db0 + dd;
      float4 a = ((const float4*)p)[0], b = ((const float4*)p)[1];
      tile[dd+0][kk] = f2bf(a.x); tile[dd+1][kk] = f2bf(a.y);
      tile[dd+2][kk] = f2bf(a.z); tile[dd+3][kk] = f2bf(a.w);
      tile[dd+4][kk] = f2bf(b.x); tile[dd+5][kk] = f2bf(b.y);
      tile[dd+6][kk] = f2bf(b.z); tile[dd+7][kk] = f2bf(b.w);
    }
    __syncthreads();
    const int d = t >> 3, k0 = (t & 7) * 8;
    unsigned short* dst = vtb + (size_t)hh*HDIM*L_ + (size_t)(db0+d)*L_ + kb0 + k0;
    if (kb0 + k0 + 8 <= CACHE_){
      *(u16x8*)dst = *(const u16x8*)&tile[d][k0];
    } else {
      #pragma unroll
      for (int e=0;e<8;++e) if (kb0 + k0 + e < CACHE_) dst[e] = tile[d][k0+e];
    }
  }
}

// ---------------- same but bf16 source (projected V) ----------------
__global__ __launch_bounds__(256) void vtrans_bf16_kernel(const unsigned short* __restrict__ src,
    unsigned short* __restrict__ vt, int R, int koff, int L_){
  __shared__ __align__(16) unsigned short tile[32][72];
  const int kb0 = blockIdx.x * 64, db0 = blockIdx.y * 32, hh = blockIdx.z;
  const int t = threadIdx.x;
  const int kk = t >> 2, dd = (t & 3) * 8;
  const int k = kb0 + kk;
  if (k < R){
    u16x8 a = *(const u16x8*)(src + (size_t)k*DIMN + hh*HDIM + db0 + dd);
    #pragma unroll
    for (int e=0;e<8;++e) tile[dd+e][kk] = a[e];
  }
  __syncthreads();
  const int d = t >> 3, k0 = (t & 7) * 8;
  unsigned short* dst = vt + (size_t)hh*HDIM*L_ + (size_t)(db0+d)*L_ + koff + kb0 + k0;
  if (kb0 + k0 + 8 <= R){
    *(u16x8*)dst = *(const u16x8*)&tile[d][k0];
  } else {
    #pragma unroll
    for (int e=0;e<8;++e) if (kb0 + k0 + e < R) dst[e] = tile[d][k0+e];
  }
}

// ---------------- fused rmsnorm + RoPE; y=0: Q path, y=1: K path ----------------
__global__ __launch_bounds__(256) void norm_rope_kernel(const unsigned short* __restrict__ lin0,
    const unsigned short* __restrict__ lin1, const float* __restrict__ gq,
    const float* __restrict__ gk, const float* __restrict__ freqs, const int* __restrict__ cur,
    unsigned short* __restrict__ qb, unsigned short* __restrict__ kb,
    int S_, int CACHE_, int L_, float qsc){
  const int q = blockIdx.x, t = threadIdx.x;
  const int path = blockIdx.y;
  const unsigned short* lin = path ? lin1 : lin0;
  const float* g = path ? gk : gq;
  unsigned short* out = path ? kb : qb;
  const size_t head_stride = path ? (size_t)L_*HDIM : (size_t)S_*HDIM;
  const int row_off = path ? CACHE_ : 0;
  const float oscale = path ? 1.0f : qsc;
  u16x8 v = *(const u16x8*)(lin + (size_t)q*DIMN + t*8);
  float x[8];
  #pragma unroll
  for (int e=0;e<8;++e) x[e] = bf2f(v[e]);
  float ss = 0.f;
  #pragma unroll
  for (int e=0;e<8;++e) ss += x[e]*x[e];
  for (int m=1;m<64;m<<=1) ss += __shfl_xor(ss, m);
  __shared__ float red[4];
  if ((t & 63) == 0) red[t>>6] = ss;
  __syncthreads();
  const float tot = red[0]+red[1]+red[2]+red[3];
  const float rstd = rsqrtf(tot * (1.0f/2048.0f) + 1e-6f);
  const int n0 = t*8;
  float xr[8];
  #pragma unroll
  for (int e=0;e<8;++e) xr[e] = x[e] * rstd * g[n0+e];
  const int pos = cur[0] + q;
  const int hh = n0 >> 7, d0 = n0 & 127;
  const float* fr = freqs + (size_t)pos * HDIM;
  float o[8];
  #pragma unroll
  for (int p=0;p<4;++p){
    const int j = (d0>>1) + p;
    const float c = fr[j], s = fr[64+j];
    o[2*p]   = xr[2*p]*c - xr[2*p+1]*s;
    o[2*p+1] = xr[2*p+1]*c + xr[2*p]*s;
  }
  u16x8 ov;
  #pragma unroll
  for (int e=0;e<8;++e) ov[e] = f2bf(o[e]*oscale);
  *(u16x8*)(out + (size_t)hh*head_stride + (size_t)(q+row_off)*HDIM + d0) = ov;
}

// ---------------- C[M,N] = A[M,K] * B[N,K]^T + bias, bf16 in fp32 out ----------------
__global__ __launch_bounds__(256,2) void gemm_bt(const unsigned short* __restrict__ A,
    const unsigned short* __restrict__ B, const float* __restrict__ bias,
    float* __restrict__ C, int M, int N, int K){
  __shared__ __align__(16) unsigned short As[2][128*64];
  __shared__ __align__(16) unsigned short Bs[2][128*64];
  const int mb = (M + 127) >> 7;
  const int swz = xcd_swz(blockIdx.x, gridDim.x);
  const int bx = swz / mb, by = swz % mb;
  const int t = threadIdx.x;
  const int w = t >> 6, lane = t & 63, lh = lane >> 4, ll = lane & 15;
  const int wr = w >> 1, wc = w & 1;
  const int m0 = by * 128, n0 = bx * 128;
  const int srow = t >> 3;
  const int scb  = (t & 7) * 16;
  const int swc  = (scb ^ ((srow & 7) << 4)) >> 1;
  int arow[4]; size_t brow[4];
  #pragma unroll
  for (int c=0;c<4;++c){
    int r = m0 + c*32 + srow; if (r >= M) r = M-1;
    arow[c] = r;
    brow[c] = (size_t)(n0 + c*32 + srow);
  }
  const int xsw = (ll & 7) << 4;
  f32x4 acc[4][4] = {};
  const int nk = K >> 6;
  auto stage = [&](int b, int kt){
    const int k0 = kt << 6;
    #pragma unroll
    for (int c=0;c<4;++c){
      gl_lds16(A + (size_t)arow[c]*K + k0 + swc, (char*)As[b] + c*4096 + w*1024);
      gl_lds16(B + brow[c]*K       + k0 + swc, (char*)Bs[b] + c*4096 + w*1024);
    }
  };
  stage(0, 0);
  asm volatile("s_waitcnt vmcnt(0)" ::: "memory");
  __syncthreads();
  int cur = 0;
  for (int kt = 0; kt < nk; ++kt){
    if (kt + 1 < nk) stage(cur ^ 1, kt + 1);
    #pragma unroll
    for (int kk=0;kk<2;++kk){
      const int cb = kk*64 + lh*16;
      bfx8 a[4], b[4];
      #pragma unroll
      for (int i=0;i<4;++i)
        a[i] = *(const bfx8*)((const char*)As[cur] + (wr*64 + i*16 + ll)*128 + (cb ^ xsw));
      #pragma unroll
      for (int j=0;j<4;++j)
        b[j] = *(const bfx8*)((const char*)Bs[cur] + (wc*64 + j*16 + ll)*128 + (cb ^ xsw));
      __builtin_amdgcn_s_setprio(1);
      #pragma unroll
      for (int i=0;i<4;++i)
        #pragma unroll
        for (int j=0;j<4;++j)
          acc[i][j] = MFMA16(a[i], b[j], acc[i][j]);
      __builtin_amdgcn_s_setprio(0);
    }
    asm volatile("s_waitcnt vmcnt(0)" ::: "memory");
    __syncthreads();
    cur ^= 1;
  }
  #pragma unroll
  for (int i=0;i<4;++i){
    #pragma unroll
    for (int j=0;j<4;++j){
      const int col = n0 + wc*64 + j*16 + ll;
      const float bb = bias[col];
      #pragma unroll
      for (int r=0;r<4;++r){
        const int row = m0 + wr*64 + i*16 + lh*4 + r;
        if (row < M) C[(size_t)row*N + col] = acc[i][j][r] + bb;
      }
    }
  }
}

// ---------------- fused QKV gemm (1D grid + XCD swizzle); dbuf; bf16 out ----------------
__global__ __launch_bounds__(256,2) void gemm_qkv(const unsigned short* __restrict__ A,
    const unsigned short* __restrict__ B0, const unsigned short* __restrict__ B1,
    const unsigned short* __restrict__ B2, const float* __restrict__ g0,
    const float* __restrict__ g1, const float* __restrict__ g2,
    unsigned short* __restrict__ C0, unsigned short* __restrict__ C1,
    unsigned short* __restrict__ C2, int M, int N, int K){
  const int mb = (M + 127) >> 7;
  const int nxt = N >> 7;
  const int per = nxt * mb;
  const int swz = xcd_swz(blockIdx.x, gridDim.x);
  const int zz = swz / per;
  const int rem = swz - zz * per;
  const int bx = rem / mb, by = rem % mb;
  const unsigned short* B = (zz==0) ? B0 : (zz==1) ? B1 : B2;
  const float* bias       = (zz==0) ? g0 : (zz==1) ? g1 : g2;
  unsigned short* C       = (zz==0) ? C0 : (zz==1) ? C1 : C2;
  __shared__ __align__(16) unsigned short As[2][128*64];
  __shared__ __align__(16) unsigned short Bs[2][128*64];
  const int t = threadIdx.x;
  const int w = t >> 6, lane = t & 63, lh = lane >> 4, ll = lane & 15;
  const int wr = w >> 1, wc = w & 1;
  const int m0 = by * 128, n0 = bx * 128;
  const int srow = t >> 3;
  const int scb  = (t & 7) * 16;
  const int swc  = (scb ^ ((srow & 7) << 4)) >> 1;
  int arow[4]; size_t brow[4];
  #pragma unroll
  for (int c=0;c<4;++c){
    int r = m0 + c*32 + srow; if (r >= M) r = M-1;
    arow[c] = r;
    brow[c] = (size_t)(n0 + c*32 + srow);
  }
  const int xsw = (ll & 7) << 4;
  f32x4 acc[4][4] = {};
  const int nk = K >> 6;
  auto stage = [&](int b, int kt){
    const int k0 = kt << 6;
    #pragma unroll
    for (int c=0;c<4;++c){
      gl_lds16(A + (size_t)arow[c]*K + k0 + swc, (char*)As[b] + c*4096 + w*1024);
      gl_lds16(B + brow[c]*K       + k0 + swc, (char*)Bs[b] + c*4096 + w*1024);
    }
  };
  stage(0, 0);
  asm volatile("s_waitcnt vmcnt(0)" ::: "memory");
  __syncthreads();
  int cur = 0;
  for (int kt = 0; kt < nk; ++kt){
    if (kt + 1 < nk) stage(cur ^ 1, kt + 1);
    #pragma unroll
    for (int kk=0;kk<2;++kk){
      const int cb = kk*64 + lh*16;
      bfx8 a[4], b[4];
      #pragma unroll
      for (int i=0;i<4;++i)
        a[i] = *(const bfx8*)((const char*)As[cur] + (wr*64 + i*16 + ll)*128 + (cb ^ xsw));
      #pragma unroll
      for (int j=0;j<4;++j)
        b[j] = *(const bfx8*)((const char*)Bs[cur] + (wc*64 + j*16 + ll)*128 + (cb ^ xsw));
      __builtin_amdgcn_s_setprio(1);
      #pragma unroll
      for (int i=0;i<4;++i)
        #pragma unroll
        for (int j=0;j<4;++j)
          acc[i][j] = MFMA16(a[i], b[j], acc[i][j]);
      __builtin_amdgcn_s_setprio(0);
    }
    asm volatile("s_waitcnt vmcnt(0)" ::: "memory");
    __syncthreads();
    cur ^= 1;
  }
  #pragma unroll
  for (int i=0;i<4;++i){
    #pragma unroll
    for (int j=0;j<4;++j){
      const int col = n0 + wc*64 + j*16 + ll;
      const float bb = bias[col];
      #pragma unroll
      for (int r=0;r<4;++r){
        const int row = m0 + wr*64 + i*16 + lh*4 + r;
        if (row < M) C[(size_t)row*N + col] = f2bf(acc[i][j][r] + bb);
      }
    }
  }
}

// ---------------- flash attention: 4 waves, 32x32x16 MFMA, gl_lds dbuf staging --------
__global__ __launch_bounds__(256,2) void attn_kernel(const unsigned short* __restrict__ Q,
    const unsigned short* __restrict__ K, const unsigned short* __restrict__ VT,
    unsigned short* __restrict__ O, float* __restrict__ pacc, float* __restrict__ pml,
    int S_, int L_, int CLn, int nx, int nsplit){
  __shared__ __align__(16) unsigned short Ks[2][64*128];
  __shared__ __align__(16) unsigned short Vs[2][128*64];
  __shared__ __align__(16) unsigned short Ps[4][32*64];
  const int nwg = gridDim.x;
  const int swzid = (blockIdx.x & 7)*(nwg >> 3) + (blockIdx.x >> 3);
  const int xq = swzid % nx;
  const int rest = swzid / nx;
  const int hh = rest % NH;
  const int z  = rest / NH;
  const int q0 = xq * 128;
  const int t = threadIdx.x, w = t >> 6, lane = t & 63;
  const int l31 = lane & 31, h = lane >> 5;
  char* Pw = (char*)Ps[w];
  const int xswp = (l31 & 7) << 4;
  const unsigned short* Qh = Q  + (size_t)hh*S_*HDIM;
  const unsigned short* Kh = K  + (size_t)hh*L_*HDIM;
  const unsigned short* Vh = VT + (size_t)hh*HDIM*L_;
  const int wrow0 = q0 + w*32;
  const int myq = wrow0 + l31;
  bfx8 qf[8];
  {
    int qr = myq; if (qr >= S_) qr = S_ - 1;
    #pragma unroll
    for (int kk=0;kk<8;++kk)
      qf[kk] = *(const bfx8*)(Qh + (size_t)qr*HDIM + kk*16 + h*8);
  }
  f32x16 acc[4] = {};
  float m_st = -1e20f, l_st = 0.f;
  int qlast = q0 + 127; if (qlast >= S_) qlast = S_ - 1;
  const int kend = CLn + qlast + 1;
  const int nt = (kend + 63) >> 6;
  const int tps = (nt + nsplit - 1) / nsplit;
  const int t0 = z * tps;
  int t1 = t0 + tps; if (t1 > nt) t1 = nt;
  const int ksrow = t >> 4;
  const int kswc  = (((t & 15)*16) ^ ((ksrow & 7) << 4)) >> 1;
  const int vsrow = t >> 3;
  const int vswc  = (((t & 7)*16) ^ ((vsrow & 7) << 4)) >> 1;

  auto stage = [&](int b, int ktile){
    const int kv0 = ktile << 6;
    #pragma unroll
    for (int c=0;c<4;++c)
      gl_lds16(Kh + (size_t)(kv0 + c*16 + ksrow)*HDIM + kswc, (char*)Ks[b] + c*4096 + w*1024);
    #pragma unroll
    for (int c=0;c<4;++c)
      gl_lds16(Vh + (size_t)(c*32 + vsrow)*L_ + kv0 + vswc, (char*)Vs[b] + c*4096 + w*1024);
  };

  if (t0 < t1) stage(0, t0);
  asm volatile("s_waitcnt vmcnt(0)" ::: "memory");
  __syncthreads();
  const int krow0 = l31,      koff0 = (krow0 & 7) << 4;
  const int krow1 = 32 + l31, koff1 = (krow1 & 7) << 4;
  int cur = 0;
  for (int kt = t0; kt < t1; ++kt){
    const int kv0 = kt << 6;
    if (kt + 1 < t1) stage(cur ^ 1, kt + 1);
    const char* Kc = (const char*)Ks[cur];
    const char* Vc = (const char*)Vs[cur];
    f32x16 sc0 = {}, sc1 = {};
    __builtin_amdgcn_s_setprio(1);
    #pragma unroll
    for (int kk=0;kk<8;++kk){
      const int cb = kk*32 + h*16;
      bfx8 kf0 = *(const bfx8*)(Kc + krow0*256 + (cb ^ koff0));
      bfx8 kf1 = *(const bfx8*)(Kc + krow1*256 + (cb ^ koff1));
      sc0 = MFMA32(kf0, qf[kk], sc0);
      sc1 = MFMA32(kf1, qf[kk], sc1);
    }
    __builtin_amdgcn_s_setprio(0);
    if (kv0 + 63 > CLn + wrow0){
      const int lim = CLn + myq;
      #pragma unroll
      for (int r=0;r<16;++r){
        const int kl = (r&3) + 8*(r>>2) + 4*h;
        if (kv0 + kl      > lim) sc0[r] = -1e30f;
        if (kv0 + 32 + kl > lim) sc1[r] = -1e30f;
      }
    }
    // row max: v_max3-friendly triples + cross-half
    float mt = sc0[0];
    #pragma unroll
    for (int r=1;r<15;r+=2) mt = fmaxf(fmaxf(sc0[r], sc0[r+1]), mt);
    mt = fmaxf(sc0[15], mt);
    #pragma unroll
    for (int r=0;r<16;r+=2) mt = fmaxf(fmaxf(sc1[r], sc1[r+1]), mt);
    mt = fmaxf(mt, __shfl_xor(mt, 32));
    mt = fmaxf(mt, -1e20f);
    if (!__all(mt - m_st <= 11.54f)){
      const float mn = fmaxf(m_st, mt);
      const float corr = exp2f(m_st - mn);
      m_st = mn;
      l_st *= corr;
      #pragma unroll
      for (int r=0;r<16;++r){
        const int qrow = (r&3) + 8*(r>>2) + 4*h;
        const float ca = __shfl(corr, qrow);
        #pragma unroll
        for (int db=0;db<4;++db) acc[db][r] *= ca;
      }
    }
    float rs = 0.f;
    #pragma unroll
    for (int r=0;r<16;++r){
      const float p0 = exp2f(sc0[r] - m_st);
      const float p1 = exp2f(sc1[r] - m_st);
      sc0[r] = p0; sc1[r] = p1;
      rs += p0 + p1;
    }
    rs += __shfl_xor(rs, 32);
    l_st += rs;
    #pragma unroll
    for (int i=0;i<4;++i){
      bf16x4 p0 = { (__bf16)sc0[4*i], (__bf16)sc0[4*i+1], (__bf16)sc0[4*i+2], (__bf16)sc0[4*i+3] };
      bf16x4 p1 = { (__bf16)sc1[4*i], (__bf16)sc1[4*i+1], (__bf16)sc1[4*i+2], (__bf16)sc1[4*i+3] };
      const int kb0b = (8*i + 4*h) * 2;
      *(bf16x4*)(Pw + l31*128 + (kb0b        ^ xswp)) = p0;
      *(bf16x4*)(Pw + l31*128 + ((64 + kb0b) ^ xswp)) = p1;
    }
    __builtin_amdgcn_s_setprio(1);
    #pragma unroll
    for (int s=0;s<4;++s){
      bfx8 pa = *(const bfx8*)(Pw + l31*128 + ((s*32 + h*16) ^ xswp));
      const int vb = s*32 + h*16;
      #pragma unroll
      for (int db=0;db<4;++db){
        const int vrow = db*32 + l31;
        bfx8 vf = *(const bfx8*)(Vc + vrow*128 + (vb ^ ((vrow & 7) << 4)));
        acc[db] = MFMA32(pa, vf, acc[db]);
      }
    }
    __builtin_amdgcn_s_setprio(0);
    asm volatile("s_waitcnt vmcnt(0)" ::: "memory");
    __syncthreads();
    cur ^= 1;
  }
  if (nsplit == 1){
    const float linv = 1.0f / l_st;
    #pragma unroll
    for (int r=0;r<16;++r){
      const int qrow = (r&3) + 8*(r>>2) + 4*h;
      const float inv = __shfl(linv, qrow);
      const int qr = wrow0 + qrow;
      if (qr < S_){
        #pragma unroll
        for (int db=0;db<4;++db)
          O[(size_t)qr*DIMN + hh*HDIM + db*32 + l31] = f2bf(acc[db][r]*inv);
      }
    }
  } else {
    #pragma unroll
    for (int r=0;r<16;++r){
      const int qrow = (r&3) + 8*(r>>2) + 4*h;
      const int qr = wrow0 + qrow;
      if (qr < S_){
        const size_t rid = ((size_t)z*NH + hh)*S_ + qr;
        float* dst = pacc + rid*128;
        #pragma unroll
        for (int db=0;db<4;++db) dst[db*32 + l31] = acc[db][r];
      }
    }
    if (lane < 32 && myq < S_){
      const size_t rid2 = ((size_t)z*NH + hh)*S_ + myq;
      pml[rid2*2]   = m_st;
      pml[rid2*2+1] = l_st;
    }
  }
}

// ---------------- combine partials -> ob bf16 (exp2 domain m) ----------------
__global__ __launch_bounds__(256) void combine_kernel(const float* __restrict__ pacc,
    const float* __restrict__ pml, unsigned short* __restrict__ ob, int S_, int nsplit){
  const int t = threadIdx.x;
  const int rid = blockIdx.x*2 + (t >> 7);   // hh*S_+q
  if (rid >= S_*NH) return;
  const int d = t & 127;
  const int hh = rid / S_;
  const int q  = rid - hh*S_;
  float M = -1e20f;
  for (int s=0; s<nsplit; ++s)
    M = fmaxf(M, pml[((size_t)s*NH*S_ + rid)*2]);
  float lt = 0.f, o = 0.f;
  for (int s=0; s<nsplit; ++s){
    const float m = pml[((size_t)s*NH*S_ + rid)*2];
    const float l = pml[((size_t)s*NH*S_ + rid)*2 + 1];
    const float wgt = exp2f(m - M);
    lt += l * wgt;
    o  += pacc[((size_t)s*NH*S_ + rid)*128 + d] * wgt;
  }
  if (lt == 0.f) lt = 1.f;
  ob[(size_t)q*DIMN + hh*HDIM + d] = f2bf(o / lt);
}

extern "C" void kernel_launch(void* const* d_in, const int* in_sizes, int n_in,
                              void* d_out, int out_size, void* d_ws, size_t ws_size,
                              hipStream_t stream){
  const float* x       = (const float*)d_in[0];
  const float* freqs   = (const float*)d_in[1];
  const float* k_cache = (const float*)d_in[2];
  const float* v_cache = (const float*)d_in[3];
  const float* Wq = (const float*)d_in[4];
  const float* bq = (const float*)d_in[5];
  const float* Wk = (const float*)d_in[6];
  const float* bk = (const float*)d_in[7];
  const float* Wv = (const float*)d_in[8];
  const float* bv = (const float*)d_in[9];
  const float* Wo = (const float*)d_in[10];
  const float* bo = (const float*)d_in[11];
  const float* gq = (const float*)d_in[12];
  const float* gk = (const float*)d_in[13];
  const int*   cur = (const int*)d_in[14];

  const int S = in_sizes[0] / DIMN;
  const int CACHE_ = in_sizes[2] / DIMN;
  const int L = CACHE_ + S;
  const int CLn = L - S;

  auto al = [](size_t n){ return (n + 255) & ~(size_t)255; };
  char* base = (char*)d_ws;
  size_t off = 0;
  auto take = [&](size_t n){ char* r = base + off; off += al(n); return r; };
  // persistent:
  unsigned short* xb  = (unsigned short*)take((size_t)S*DIMN*2);
  unsigned short* Wob = (unsigned short*)take((size_t)DIMN*DIMN*2);
  unsigned short* qb  = (unsigned short*)take((size_t)NH*S*HDIM*2);
  unsigned short* kb  = (unsigned short*)take((size_t)NH*L*HDIM*2);
  unsigned short* vtb = (unsigned short*)take((size_t)NH*HDIM*L*2);
  unsigned short* ob  = (unsigned short*)take((size_t)S*DIMN*2);
  const size_t ubase = off;
  // union pool A: transients (dead before attn): lin0/1/2 (bf16) + Wq/Wk/Wv (bf16)
  const size_t l_sz = al((size_t)S*DIMN*2);
  const size_t w_sz = al((size_t)DIMN*DIMN*2);
  unsigned short* lin0 = (unsigned short*)(base + ubase);
  unsigned short* lin1 = (unsigned short*)(base + ubase + l_sz);
  unsigned short* lin2 = (unsigned short*)(base + ubase + 2*l_sz);
  unsigned short* Wqb  = (unsigned short*)(base + ubase + 3*l_sz);
  unsigned short* Wkb  = (unsigned short*)(base + ubase + 3*l_sz + w_sz);
  unsigned short* Wvb  = (unsigned short*)(base + ubase + 3*l_sz + 2*w_sz);
  const size_t trans_sz = 3*l_sz + 3*w_sz;
  // union pool B: attention partials
  auto pool_sz = [&](int ns){
    return al((size_t)ns*NH*S*HDIM*4) + al((size_t)ns*NH*S*2*4);
  };
  int nsplit = 1;
  if (ubase + (trans_sz > pool_sz(4) ? trans_sz : pool_sz(4)) <= ws_size) nsplit = 4;
  else if (ubase + (trans_sz > pool_sz(2) ? trans_sz : pool_sz(2)) <= ws_size) nsplit = 2;
  if (ubase + trans_sz > ws_size) return;
  float* pacc = (float*)(base + ubase);
  float* pml  = (float*)(base + ubase + al((size_t)nsplit*NH*S*HDIM*4));

  // merged prep: x/W casts + kcache + v_cache transpose
  const int WB = (DIMN*DIMN/8)/256;
  const int nkb = (CACHE_ + 63) >> 6;
  const int prep_blocks = S + 4*WB + CACHE_ + nkb*4*NH;
  prep_kernel<<<prep_blocks, 256, 0, stream>>>(x, Wq, Wk, Wv, Wo, k_cache, v_cache,
                                               xb, Wqb, Wkb, Wvb, Wob, kb, vtb,
                                               S, CACHE_, L);

  const int mb = (S+127)/128;
  gemm_qkv<<<(DIMN/128)*mb*3, 256, 0, stream>>>(xb, Wqb, Wkb, Wvb, bq, bk, bv,
                                                lin0, lin1, lin2, S, DIMN, DIMN);
  const float qsc = 0.08838834764831845f * 1.4426950408889634f;
  norm_rope_kernel<<<dim3(S,2), 256, 0, stream>>>(lin0, lin1, gq, gk, freqs, cur,
                                                  qb, kb, S, CACHE_, L, qsc);
  vtrans_bf16_kernel<<<dim3((S+63)/64, 4, NH), 256, 0, stream>>>(lin2, vtb, S, CACHE_, L);

  const int nx = (S+127)/128;
  attn_kernel<<<nx*NH*nsplit, 256, 0, stream>>>(qb, kb, vtb, ob,
                                                pacc, pml, S, L, CLn, nx, nsplit);
  if (nsplit > 1)
    combine_kernel<<<(S*NH+1)/2, 256, 0, stream>>>(pacc, pml, ob, S, nsplit);
  gemm_bt<<<(DIMN/128)*mb, 256, 0, stream>>>(ob, Wob, bo, (float*)d_out, S, DIMN, DIMN);
}